// Round 8
// baseline (478.292 us; speedup 1.0000x reference)
//
#include <hip/hip_runtime.h>
#include <math.h>

#define N_NODES 100000
#define N_EDGES 1600000
#define DIN 128
#define DH 32
#define NEG_SLOPE 0.2f
#define BN_EPS 1e-5f
#define MT 64        // nodes per transform block
#define BSHIFT 9     // 512 nodes per bucket
#define NBUCK 196    // ceil(N_NODES / 512)
#define B_SCAT 256   // blocks for bucket hist/scatter
#define CPB ((N_EDGES + B_SCAT - 1) / B_SCAT)

typedef __attribute__((ext_vector_type(8))) short short8;
typedef __attribute__((ext_vector_type(4))) float f32x4;

__device__ __forceinline__ unsigned short f2bf(float f) {
    unsigned int u = __float_as_uint(f);
    u = (u + 0x7FFFu + ((u >> 16) & 1u)) >> 16;
    return (unsigned short)u;
}
__device__ __forceinline__ float bf2f(unsigned short h) {
    return __uint_as_float((unsigned int)h << 16);
}
__device__ __forceinline__ unsigned short f2h(float f) {
    _Float16 hv = (_Float16)f;
    return __builtin_bit_cast(unsigned short, hv);
}
__device__ __forceinline__ float h2f(unsigned short h) {
    return (float)__builtin_bit_cast(_Float16, h);
}

// ---------------- CSR build: two-level counting sort ----------------
// Phase 1: per-block bucket histograms

__global__ __launch_bounds__(256) void bucket_hist_kernel(
    const int* __restrict__ dst, int* __restrict__ bh, int e) {
    __shared__ int lh[NBUCK];
    for (int j = threadIdx.x; j < NBUCK; j += 256) lh[j] = 0;
    __syncthreads();
    int b = blockIdx.x;
    int lo = b * CPB, hi = min(lo + CPB, e);
    for (int i = lo + threadIdx.x; i < hi; i += 256)
        atomicAdd(&lh[dst[i] >> BSHIFT], 1);
    __syncthreads();
    for (int j = threadIdx.x; j < NBUCK; j += 256) bh[j * B_SCAT + b] = lh[j];
}

// Phase 2: exclusive scan over NBUCK*B_SCAT counters (bucket-major)
__global__ __launch_bounds__(1024) void bucket_scan_kernel(
    const int* __restrict__ bh, int* __restrict__ bs, int total) {
    __shared__ int part[1024];
    int t = threadIdx.x;
    int chunk = (total + 1023) >> 10;
    int lo = t * chunk, hi = min(lo + chunk, total);
    int s = 0;
    for (int i = lo; i < hi; ++i) s += bh[i];
    part[t] = s;
    __syncthreads();
    for (int d = 1; d < 1024; d <<= 1) {
        int v = (t >= d) ? part[t - d] : 0;
        __syncthreads();
        part[t] += v;
        __syncthreads();
    }
    int run = t ? part[t - 1] : 0;
    for (int i = lo; i < hi; ++i) { int v = bh[i]; bs[i] = run; run += v; }
}

// Phase 3: bucketed scatter; each (block,bucket) region is private+contiguous.
// rec.y stores the kv-index (src*2 + rel) directly.
__global__ __launch_bounds__(256) void bucket_scatter_kernel(
    const int* __restrict__ src, const int* __restrict__ dst, const int* __restrict__ et,
    const int* __restrict__ bs, int2* __restrict__ rec, int e) {
    __shared__ int cur[NBUCK];
    int b = blockIdx.x;
    for (int j = threadIdx.x; j < NBUCK; j += 256) cur[j] = bs[j * B_SCAT + b];
    __syncthreads();
    int lo = b * CPB, hi = min(lo + CPB, e);
    for (int i = lo + threadIdx.x; i < hi; i += 256) {
        int d = dst[i];
        int pos = atomicAdd(&cur[d >> BSHIFT], 1);
        rec[pos] = make_int2(d, (src[i] << 1) | et[i]);
    }
}

// Phase 4: fine scatter within each bucket; also derives per-node degrees,
// block-scans them, and writes the CSR off[] — no separate deg/scan kernels.
__global__ __launch_bounds__(256) void fine_scatter_kernel(
    const int2* __restrict__ rec, const int* __restrict__ bs,
    int* __restrict__ off, int* __restrict__ packed, int n, int e) {
    __shared__ int ldeg[1 << BSHIFT];
    __shared__ int lpos[1 << BSHIFT];
    int k = blockIdx.x, t = threadIdx.x;
    int nb0 = k << BSHIFT;
    ldeg[t] = 0;
    ldeg[t + 256] = 0;
    __syncthreads();
    int start = bs[k * B_SCAT];
    int end = (k + 1 < NBUCK) ? bs[(k + 1) * B_SCAT] : e;
    for (int i = start + t; i < end; i += 256)
        atomicAdd(&ldeg[rec[i].x - nb0], 1);
    __syncthreads();
    lpos[t] = ldeg[t];
    lpos[t + 256] = ldeg[t + 256];
    __syncthreads();
    for (int d = 1; d < (1 << BSHIFT); d <<= 1) {
        int v0 = (t >= d) ? lpos[t - d] : 0;
        int v1 = (t + 256 >= d) ? lpos[t + 256 - d] : 0;
        __syncthreads();
        lpos[t] += v0;
        lpos[t + 256] += v1;
        __syncthreads();
    }
    int e0 = lpos[t] - ldeg[t];          // exclusive
    int e1 = lpos[t + 256] - ldeg[t + 256];
    __syncthreads();
    lpos[t] = start + e0;
    lpos[t + 256] = start + e1;
    int node0 = nb0 + t, node1 = nb0 + t + 256;
    if (node0 < n) off[node0] = start + e0;
    if (node1 < n) off[node1] = start + e1;
    if (k == 0 && t == 0) off[n] = e;
    __syncthreads();
    for (int i = start + t; i < end; i += 256) {
        int2 r = rec[i];
        int pos = atomicAdd(&lpos[r.x - nb0], 1);
        packed[pos] = r.y;
    }
}

// -------- weight conversion (all 3 layers in one launch) ----------------
// Wt[col][k] = split-bf16 of w[r][k][c], col=r*32+c

__global__ void wconv_all_kernel(
    const float* __restrict__ w0, unsigned short* __restrict__ wt0h, unsigned short* __restrict__ wt0l,
    const float* __restrict__ w1, unsigned short* __restrict__ wt1h, unsigned short* __restrict__ wt1l,
    const float* __restrict__ w2, unsigned short* __restrict__ wt2h, unsigned short* __restrict__ wt2l) {
    int i = blockIdx.x * blockDim.x + threadIdx.x;
    const float* w;
    unsigned short *wh, *wl;
    int K, idx;
    if (i < 64 * DIN) { w = w0; wh = wt0h; wl = wt0l; K = DIN; idx = i; }
    else if (i < 64 * DIN + 64 * DH) { w = w1; wh = wt1h; wl = wt1l; K = DH; idx = i - 64 * DIN; }
    else if (i < 64 * DIN + 128 * DH) { w = w2; wh = wt2h; wl = wt2l; K = DH; idx = i - 64 * DIN - 64 * DH; }
    else return;
    int col = idx / K, k = idx % K;
    int r = col >> 5, c = col & 31;
    float v = w[(r * K + k) * DH + c];
    unsigned short h = f2bf(v);
    wh[idx] = h;
    wl[idx] = f2bf(v - bf2f(h));
}

// ---------------- MFMA transform: y[node][64] = X[node][K] @ Wmat[K][64] ----------
// Split-bf16 (hi+lo) on both operands: acc = aH*bH + aH*bL + aL*bH  (~fp32 accuracy).
// y is stored in fp16 (V side of attention); q/k row-dots stay fp32-exact.

template<int K, bool FUSE_BN>
__global__ __launch_bounds__(256) void transform_mfma_kernel(
    const float* __restrict__ xin, const float* __restrict__ stats,
    const float* __restrict__ gamma, const float* __restrict__ beta,
    const unsigned short* __restrict__ WtHi, const unsigned short* __restrict__ WtLo,
    const float* __restrict__ Qw, const float* __restrict__ Kw,
    unsigned short* __restrict__ yb, float* __restrict__ qv, float* __restrict__ kv, int n) {
    constexpr int LDK = K + 8;          // +8 elems (16B) pad -> bank spread
    constexpr int KT = K / 32;
    __shared__ unsigned short xs_hi[MT * LDK];
    __shared__ unsigned short xs_lo[MT * LDK];
    __shared__ float scs[DH], shs[DH];
    int tid = threadIdx.x;
    int base = blockIdx.x * MT;

    if (FUSE_BN) {
        if (tid < DH) {
            float mu = stats[tid] * (1.f / N_NODES);
            float var = stats[DH + tid] * (1.f / N_NODES) - mu * mu;
            float inv = rsqrtf(var + BN_EPS);
            float sc = gamma[tid] * inv;
            scs[tid] = sc;
            shs[tid] = beta[tid] - mu * sc;
        }
        __syncthreads();
    }

    // stage X tile (fp32 -> hi/lo bf16) into LDS
    constexpr int CH = K / 4;
    for (int c = tid; c < MT * CH; c += 256) {
        int row = c / CH, c4 = c % CH;
        int node = base + row;
        float4 v = make_float4(0.f, 0.f, 0.f, 0.f);
        if (node < n) v = ((const float4*)(xin + (size_t)node * K))[c4];
        if (FUSE_BN) {
            int c0 = c4 * 4;
            v.x = v.x * scs[c0 + 0] + shs[c0 + 0];
            v.y = v.y * scs[c0 + 1] + shs[c0 + 1];
            v.z = v.z * scs[c0 + 2] + shs[c0 + 2];
            v.w = v.w * scs[c0 + 3] + shs[c0 + 3];
        }
        ushort4 hb = make_ushort4(f2bf(v.x), f2bf(v.y), f2bf(v.z), f2bf(v.w));
        ushort4 lb = make_ushort4(f2bf(v.x - bf2f(hb.x)), f2bf(v.y - bf2f(hb.y)),
                                  f2bf(v.z - bf2f(hb.z)), f2bf(v.w - bf2f(hb.w)));
        *(ushort4*)(&xs_hi[row * LDK + c4 * 4]) = hb;
        *(ushort4*)(&xs_lo[row * LDK + c4 * 4]) = lb;
    }
    __syncthreads();

    int lane = tid & 63;
    int wave = tid >> 6;                 // 4 waves x 16 rows
    int r16 = lane & 15, g = lane >> 4;  // frag coords
    int wrow = wave * 16;

    f32x4 acc[4];
#pragma unroll
    for (int nt = 0; nt < 4; ++nt) acc[nt] = f32x4{0.f, 0.f, 0.f, 0.f};

#pragma unroll
    for (int kt = 0; kt < KT; ++kt) {
        short8 a_hi = *(const short8*)(&xs_hi[(wrow + r16) * LDK + kt * 32 + g * 8]);
        short8 a_lo = *(const short8*)(&xs_lo[(wrow + r16) * LDK + kt * 32 + g * 8]);
#pragma unroll
        for (int nt = 0; nt < 4; ++nt) {
            const size_t bo = (size_t)(nt * 16 + r16) * K + kt * 32 + g * 8;
            short8 b_hi = *(const short8*)(WtHi + bo);
            short8 b_lo = *(const short8*)(WtLo + bo);
            acc[nt] = __builtin_amdgcn_mfma_f32_16x16x32_bf16(a_hi, b_hi, acc[nt], 0, 0, 0);
            acc[nt] = __builtin_amdgcn_mfma_f32_16x16x32_bf16(a_hi, b_lo, acc[nt], 0, 0, 0);
            acc[nt] = __builtin_amdgcn_mfma_f32_16x16x32_bf16(a_lo, b_hi, acc[nt], 0, 0, 0);
        }
    }

    // epilogue: fp16 y stores + fused fp32 q/k row-dots
    float qp[2][4] = {{0.f, 0.f, 0.f, 0.f}, {0.f, 0.f, 0.f, 0.f}};
    float kp[2][4] = {{0.f, 0.f, 0.f, 0.f}, {0.f, 0.f, 0.f, 0.f}};
#pragma unroll
    for (int nt = 0; nt < 4; ++nt) {
        int col = nt * 16 + r16;
        int rr = col >> 5, cc = col & 31;
        float qw = Qw[rr * DH + cc], kw = Kw[rr * DH + cc];
#pragma unroll
        for (int j = 0; j < 4; ++j) {
            float v = acc[nt][j];
            qp[rr][j] += v * qw;
            kp[rr][j] += v * kw;
            int node = base + wrow + g * 4 + j;
            if (node < n) yb[(size_t)node * 64 + col] = f2h(v);
        }
    }
#pragma unroll
    for (int j = 0; j < 4; ++j) {
#pragma unroll
        for (int rr = 0; rr < 2; ++rr) {
            float q = qp[rr][j], k = kp[rr][j];
            for (int d = 8; d; d >>= 1) {
                q += __shfl_xor(q, d, 16);
                k += __shfl_xor(k, d, 16);
            }
            if (r16 == 0) {
                int node = base + wrow + g * 4 + j;
                if (node < n) {
                    qv[node * 2 + rr] = q;
                    kv[node * 2 + rr] = k;
                }
            }
        }
    }
}

// ---------------- fused attention + aggregate + relu + BN stats ----------------
// Single sweep; y gathered as fp16 (64B row = one cache line), weights fp32.
// packed[] stores kv-index (src*2+rel): kvidx = p, row = p<<5, rel = p&1.
// Streaming data (packed, hpre) uses non-temporal ops to keep L2 for y rows.

__global__ __launch_bounds__(256) void attn_kernel(
    const int* __restrict__ off, const int* __restrict__ packed,
    const unsigned short* __restrict__ y, const float* __restrict__ qv,
    const float* __restrict__ kv, const float* __restrict__ bias,
    float* __restrict__ hpre, float* __restrict__ stats, int n) {
    __shared__ float ssum[DH], ssq[DH];
    if (threadIdx.x < DH) { ssum[threadIdx.x] = 0.f; ssq[threadIdx.x] = 0.f; }
    __syncthreads();
    int lane = threadIdx.x & 31;
    int sub = threadIdx.x >> 5;
    int spb = blockDim.x >> 5;
    float rsum = 0.f, rsq = 0.f;
    float bl = bias[lane];
    for (int node = blockIdx.x * spb + sub; node < n; node += gridDim.x * spb) {
        int lo = off[node], hi = off[node + 1];
        float q0 = qv[node * 2], q1 = qv[node * 2 + 1];
        float acc0 = 0.f, acc1 = 0.f, acc2 = 0.f, acc3 = 0.f, wsum = 0.f;
        for (int base = lo; base < hi; base += 32) {
            int i = base + lane;
            float w = 0.f;
            int row = 0;
            if (i < hi) {
                int p = __builtin_nontemporal_load(packed + i);
                float ev = ((p & 1) ? q1 : q0) + kv[p];
                ev = ev > 0.f ? ev : NEG_SLOPE * ev;
                w = __expf(ev - 8.f);
                row = p << 5;
            }
            wsum += w;
            int cnt = min(32, hi - base);
            int j = 0;
            for (; j + 4 <= cnt; j += 4) {
                float w0 = __shfl(w, j, 32),     w1 = __shfl(w, j + 1, 32);
                float w2 = __shfl(w, j + 2, 32), w3 = __shfl(w, j + 3, 32);
                int r0 = __shfl(row, j, 32),     r1 = __shfl(row, j + 1, 32);
                int r2 = __shfl(row, j + 2, 32), r3 = __shfl(row, j + 3, 32);
                acc0 += w0 * h2f(y[r0 + lane]);
                acc1 += w1 * h2f(y[r1 + lane]);
                acc2 += w2 * h2f(y[r2 + lane]);
                acc3 += w3 * h2f(y[r3 + lane]);
            }
            for (; j < cnt; ++j) {
                float w0 = __shfl(w, j, 32);
                int r0 = __shfl(row, j, 32);
                acc0 += w0 * h2f(y[r0 + lane]);
            }
        }
        for (int d = 16; d; d >>= 1) wsum += __shfl_xor(wsum, d, 32);
        float h = fmaxf((acc0 + acc1 + acc2 + acc3) / (wsum + 1e-16f) + bl, 0.f);
        __builtin_nontemporal_store(h, &hpre[(size_t)node * DH + lane]);
        rsum += h;
        rsq += h * h;
    }
    atomicAdd(&ssum[lane], rsum);
    atomicAdd(&ssq[lane], rsq);
    __syncthreads();
    if (threadIdx.x < DH) {
        atomicAdd(&stats[threadIdx.x], ssum[threadIdx.x]);
        atomicAdd(&stats[DH + threadIdx.x], ssq[threadIdx.x]);
    }
}

// ---------------- final BN + MLP head ----------------

__global__ __launch_bounds__(256) void mlp_kernel(
    const float* __restrict__ hpre, const float* __restrict__ stats,
    const float* __restrict__ gamma, const float* __restrict__ beta,
    const float* __restrict__ mw1, const float* __restrict__ mb1,
    const float* __restrict__ mw2, const float* __restrict__ mb2,
    float* __restrict__ out, int n) {
    int g = (blockIdx.x * blockDim.x + threadIdx.x) >> 5;
    int lane = threadIdx.x & 31;
    if (g >= n) return;
    float mu = stats[lane] * (1.f / N_NODES);
    float var = stats[DH + lane] * (1.f / N_NODES) - mu * mu;
    float inv = rsqrtf(var + BN_EPS);
    float h = gamma[lane] * (hpre[(size_t)g * DH + lane] - mu) * inv + beta[lane];
    float a = mb1[lane];
#pragma unroll
    for (int f = 0; f < DH; ++f) a += __shfl(h, f, 32) * mw1[f * DH + lane];
    float s = 1.f / (1.f + __expf(-a));
    float o0 = s * mw2[lane * 2 + 0];
    float o1 = s * mw2[lane * 2 + 1];
    for (int d = 16; d; d >>= 1) {
        o0 += __shfl_xor(o0, d, 32);
        o1 += __shfl_xor(o1, d, 32);
    }
    if (lane == 0) {
        out[(size_t)g * 2 + 0] = o0 + mb2[0];
        out[(size_t)g * 2 + 1] = o1 + mb2[1];
    }
}

// ---------------- launch ----------------

extern "C" void kernel_launch(void* const* d_in, const int* in_sizes, int n_in,
                              void* d_out, int out_size, void* d_ws, size_t ws_size,
                              hipStream_t stream) {
    const float* x = (const float*)d_in[0];
    const int* edge_index = (const int*)d_in[1];
    const int* edge_type = (const int*)d_in[2];
    const float* w[3]  = {(const float*)d_in[3],  (const float*)d_in[9],  (const float*)d_in[15]};
    const float* aq[3] = {(const float*)d_in[4],  (const float*)d_in[10], (const float*)d_in[16]};
    const float* ak[3] = {(const float*)d_in[5],  (const float*)d_in[11], (const float*)d_in[17]};
    const float* bb[3] = {(const float*)d_in[6],  (const float*)d_in[12], (const float*)d_in[18]};
    const float* gm[3] = {(const float*)d_in[7],  (const float*)d_in[13], (const float*)d_in[19]};
    const float* be[3] = {(const float*)d_in[8],  (const float*)d_in[14], (const float*)d_in[20]};
    const float* mw1 = (const float*)d_in[21];
    const float* mb1 = (const float*)d_in[22];
    const float* mw2 = (const float*)d_in[23];
    const float* mb2 = (const float*)d_in[24];
    float* out = (float*)d_out;

    const int n = N_NODES, e = N_EDGES;
    char* ws = (char*)d_ws;
    auto alloc = [&](size_t bytes) {
        char* p = ws;
        ws += (bytes + 255) & ~(size_t)255;
        return p;
    };
    int* off      = (int*)alloc((size_t)(n + 1) * 4);
    int* bhist    = (int*)alloc((size_t)NBUCK * B_SCAT * 4);
    int* bscan    = (int*)alloc((size_t)NBUCK * B_SCAT * 4);
    int2* rec     = (int2*)alloc((size_t)e * 8);
    int* packed   = (int*)alloc((size_t)e * 4);
    unsigned short* yb = (unsigned short*)alloc((size_t)n * 2 * DH * 2);
    float* qv     = (float*)alloc((size_t)n * 2 * 4);
    float* kv     = (float*)alloc((size_t)n * 2 * 4);
    float* hpre   = (float*)alloc((size_t)n * DH * 4);
    float* stats  = (float*)alloc(3 * 2 * DH * 4);
    unsigned short* wt0h = (unsigned short*)alloc((size_t)64 * DIN * 2);
    unsigned short* wt0l = (unsigned short*)alloc((size_t)64 * DIN * 2);
    unsigned short* wt1h = (unsigned short*)alloc((size_t)64 * DH * 2);
    unsigned short* wt1l = (unsigned short*)alloc((size_t)64 * DH * 2);
    unsigned short* wt2h = (unsigned short*)alloc((size_t)64 * DH * 2);
    unsigned short* wt2l = (unsigned short*)alloc((size_t)64 * DH * 2);

    hipMemsetAsync(stats, 0, 3 * 2 * DH * 4, stream);

    const int* src = edge_index;
    const int* dst = edge_index + e;

    wconv_all_kernel<<<(64 * DIN + 128 * DH + 255) / 256, 256, 0, stream>>>(
        w[0], wt0h, wt0l, w[1], wt1h, wt1l, w[2], wt2h, wt2l);

    // CSR build: bucket hist, bucket scan, bucketed scatter, fine scatter(+off)
    bucket_hist_kernel<<<B_SCAT, 256, 0, stream>>>(dst, bhist, e);
    bucket_scan_kernel<<<1, 1024, 0, stream>>>(bhist, bscan, NBUCK * B_SCAT);
    bucket_scatter_kernel<<<B_SCAT, 256, 0, stream>>>(src, dst, edge_type, bscan, rec, e);
    fine_scatter_kernel<<<NBUCK, 256, 0, stream>>>(rec, bscan, off, packed, n, e);

    int tblocks = (n + MT - 1) / MT;

    // layer 0
    transform_mfma_kernel<DIN, false><<<tblocks, 256, 0, stream>>>(
        x, nullptr, nullptr, nullptr, wt0h, wt0l, aq[0], ak[0], yb, qv, kv, n);
    attn_kernel<<<2048, 256, 0, stream>>>(off, packed, yb, qv, kv, bb[0], hpre, stats + 0 * 64, n);

    // layer 1
    transform_mfma_kernel<DH, true><<<tblocks, 256, 0, stream>>>(
        hpre, stats + 0 * 64, gm[0], be[0], wt1h, wt1l, aq[1], ak[1], yb, qv, kv, n);
    attn_kernel<<<2048, 256, 0, stream>>>(off, packed, yb, qv, kv, bb[1], hpre, stats + 1 * 64, n);

    // layer 2
    transform_mfma_kernel<DH, true><<<tblocks, 256, 0, stream>>>(
        hpre, stats + 1 * 64, gm[1], be[1], wt2h, wt2l, aq[2], ak[2], yb, qv, kv, n);
    attn_kernel<<<2048, 256, 0, stream>>>(off, packed, yb, qv, kv, bb[2], hpre, stats + 2 * 64, n);

    // final BN + MLP head
    mlp_kernel<<<((size_t)n * 32 + 255) / 256, 256, 0, stream>>>(
        hpre, stats + 2 * 64, gm[2], be[2], mw1, mb1, mw2, mb2, out, n);
}

// Round 9
// 456.452 us; speedup vs baseline: 1.0478x; 1.0478x over previous
//
#include <hip/hip_runtime.h>
#include <math.h>

#define N_NODES 100000
#define N_EDGES 1600000
#define DIN 128
#define DH 32
#define NEG_SLOPE 0.2f
#define BN_EPS 1e-5f
#define MT 64        // nodes per transform block
#define BSHIFT 9     // 512 nodes per bucket
#define NBUCK 196    // ceil(N_NODES / 512)
#define B_SCAT 256   // blocks for bucket hist/scatter
#define CPB ((N_EDGES + B_SCAT - 1) / B_SCAT)
#define WCONV_ELEMS (64 * DIN + 128 * DH)   // 12288
#define WCONV_BLOCKS ((WCONV_ELEMS + 255) / 256)

typedef __attribute__((ext_vector_type(8))) short short8;
typedef __attribute__((ext_vector_type(4))) float f32x4;

__device__ __forceinline__ unsigned short f2bf(float f) {
    unsigned int u = __float_as_uint(f);
    u = (u + 0x7FFFu + ((u >> 16) & 1u)) >> 16;
    return (unsigned short)u;
}
__device__ __forceinline__ float bf2f(unsigned short h) {
    return __uint_as_float((unsigned int)h << 16);
}
__device__ __forceinline__ unsigned short f2h(float f) {
    _Float16 hv = (_Float16)f;
    return __builtin_bit_cast(unsigned short, hv);
}
__device__ __forceinline__ float h2f(unsigned short h) {
    return (float)__builtin_bit_cast(_Float16, h);
}

// ---------------- shared transform body (MFMA, split-bf16) ----------------
// y[node][64] = X[node][K] @ Wmat[K][64]; y stored fp16; q/k row-dots fp32.

template<int K, bool FUSE_BN>
__device__ __forceinline__ void transform_body(
    const float* __restrict__ xin, const float* __restrict__ stats,
    const float* __restrict__ gamma, const float* __restrict__ beta,
    const unsigned short* __restrict__ WtHi, const unsigned short* __restrict__ WtLo,
    const float* __restrict__ Qw, const float* __restrict__ Kw,
    unsigned short* __restrict__ yb, float* __restrict__ qv, float* __restrict__ kv,
    int tile, int n) {
    constexpr int LDK = K + 8;
    constexpr int KT = K / 32;
    __shared__ unsigned short xs_hi[MT * LDK];
    __shared__ unsigned short xs_lo[MT * LDK];
    __shared__ float scs[DH], shs[DH];
    int tid = threadIdx.x;
    int base = tile * MT;

    if (FUSE_BN) {
        if (tid < DH) {
            float mu = stats[tid] * (1.f / N_NODES);
            float var = stats[DH + tid] * (1.f / N_NODES) - mu * mu;
            float inv = rsqrtf(var + BN_EPS);
            float sc = gamma[tid] * inv;
            scs[tid] = sc;
            shs[tid] = beta[tid] - mu * sc;
        }
        __syncthreads();
    }

    constexpr int CH = K / 4;
    for (int c = tid; c < MT * CH; c += 256) {
        int row = c / CH, c4 = c % CH;
        int node = base + row;
        float4 v = make_float4(0.f, 0.f, 0.f, 0.f);
        if (node < n) v = ((const float4*)(xin + (size_t)node * K))[c4];
        if (FUSE_BN) {
            int c0 = c4 * 4;
            v.x = v.x * scs[c0 + 0] + shs[c0 + 0];
            v.y = v.y * scs[c0 + 1] + shs[c0 + 1];
            v.z = v.z * scs[c0 + 2] + shs[c0 + 2];
            v.w = v.w * scs[c0 + 3] + shs[c0 + 3];
        }
        ushort4 hb = make_ushort4(f2bf(v.x), f2bf(v.y), f2bf(v.z), f2bf(v.w));
        ushort4 lb = make_ushort4(f2bf(v.x - bf2f(hb.x)), f2bf(v.y - bf2f(hb.y)),
                                  f2bf(v.z - bf2f(hb.z)), f2bf(v.w - bf2f(hb.w)));
        *(ushort4*)(&xs_hi[row * LDK + c4 * 4]) = hb;
        *(ushort4*)(&xs_lo[row * LDK + c4 * 4]) = lb;
    }
    __syncthreads();

    int lane = tid & 63;
    int wave = tid >> 6;
    int r16 = lane & 15, g = lane >> 4;
    int wrow = wave * 16;

    f32x4 acc[4];
#pragma unroll
    for (int nt = 0; nt < 4; ++nt) acc[nt] = f32x4{0.f, 0.f, 0.f, 0.f};

#pragma unroll
    for (int kt = 0; kt < KT; ++kt) {
        short8 a_hi = *(const short8*)(&xs_hi[(wrow + r16) * LDK + kt * 32 + g * 8]);
        short8 a_lo = *(const short8*)(&xs_lo[(wrow + r16) * LDK + kt * 32 + g * 8]);
#pragma unroll
        for (int nt = 0; nt < 4; ++nt) {
            const size_t bo = (size_t)(nt * 16 + r16) * K + kt * 32 + g * 8;
            short8 b_hi = *(const short8*)(WtHi + bo);
            short8 b_lo = *(const short8*)(WtLo + bo);
            acc[nt] = __builtin_amdgcn_mfma_f32_16x16x32_bf16(a_hi, b_hi, acc[nt], 0, 0, 0);
            acc[nt] = __builtin_amdgcn_mfma_f32_16x16x32_bf16(a_hi, b_lo, acc[nt], 0, 0, 0);
            acc[nt] = __builtin_amdgcn_mfma_f32_16x16x32_bf16(a_lo, b_hi, acc[nt], 0, 0, 0);
        }
    }

    float qp[2][4] = {{0.f, 0.f, 0.f, 0.f}, {0.f, 0.f, 0.f, 0.f}};
    float kp[2][4] = {{0.f, 0.f, 0.f, 0.f}, {0.f, 0.f, 0.f, 0.f}};
#pragma unroll
    for (int nt = 0; nt < 4; ++nt) {
        int col = nt * 16 + r16;
        int rr = col >> 5, cc = col & 31;
        float qw = Qw[rr * DH + cc], kw = Kw[rr * DH + cc];
#pragma unroll
        for (int j = 0; j < 4; ++j) {
            float v = acc[nt][j];
            qp[rr][j] += v * qw;
            kp[rr][j] += v * kw;
            int node = base + wrow + g * 4 + j;
            if (node < n) yb[(size_t)node * 64 + col] = f2h(v);
        }
    }
#pragma unroll
    for (int j = 0; j < 4; ++j) {
#pragma unroll
        for (int rr = 0; rr < 2; ++rr) {
            float q = qp[rr][j], k = kp[rr][j];
            for (int d = 8; d; d >>= 1) {
                q += __shfl_xor(q, d, 16);
                k += __shfl_xor(k, d, 16);
            }
            if (r16 == 0) {
                int node = base + wrow + g * 4 + j;
                if (node < n) {
                    qv[node * 2 + rr] = q;
                    kv[node * 2 + rr] = k;
                }
            }
        }
    }
}

// ---------------- K1: bucket hist + weight conversion + stats zero ----------------

__global__ __launch_bounds__(256) void hist_wconv_kernel(
    const int* __restrict__ dst, int* __restrict__ bh, int e,
    const float* __restrict__ w0, unsigned short* __restrict__ wt0h, unsigned short* __restrict__ wt0l,
    const float* __restrict__ w1, unsigned short* __restrict__ wt1h, unsigned short* __restrict__ wt1l,
    const float* __restrict__ w2, unsigned short* __restrict__ wt2h, unsigned short* __restrict__ wt2l,
    float* __restrict__ stats) {
    if (blockIdx.x < B_SCAT) {
        __shared__ int lh[NBUCK];
        for (int j = threadIdx.x; j < NBUCK; j += 256) lh[j] = 0;
        __syncthreads();
        int b = blockIdx.x;
        int lo = b * CPB, hi = min(lo + CPB, e);
        for (int i = lo + threadIdx.x; i < hi; i += 256)
            atomicAdd(&lh[dst[i] >> BSHIFT], 1);
        __syncthreads();
        for (int j = threadIdx.x; j < NBUCK; j += 256) bh[j * B_SCAT + b] = lh[j];
    } else {
        int i = (blockIdx.x - B_SCAT) * 256 + threadIdx.x;
        if (blockIdx.x == B_SCAT && threadIdx.x < 3 * 2 * DH) stats[threadIdx.x] = 0.f;
        const float* w;
        unsigned short *wh, *wl;
        int K, idx;
        if (i < 64 * DIN) { w = w0; wh = wt0h; wl = wt0l; K = DIN; idx = i; }
        else if (i < 64 * DIN + 64 * DH) { w = w1; wh = wt1h; wl = wt1l; K = DH; idx = i - 64 * DIN; }
        else if (i < 64 * DIN + 128 * DH) { w = w2; wh = wt2h; wl = wt2l; K = DH; idx = i - 64 * DIN - 64 * DH; }
        else return;
        int col = idx / K, k = idx % K;
        int r = col >> 5, c = col & 31;
        float v = w[(r * K + k) * DH + c];
        unsigned short h = f2bf(v);
        wh[idx] = h;
        wl[idx] = f2bf(v - bf2f(h));
    }
}

// ---------------- K2: exclusive scan over NBUCK*B_SCAT counters ----------------

__global__ __launch_bounds__(1024) void bucket_scan_kernel(
    const int* __restrict__ bh, int* __restrict__ bs, int total) {
    __shared__ int part[1024];
    int t = threadIdx.x;
    int chunk = (total + 1023) >> 10;
    int lo = t * chunk, hi = min(lo + chunk, total);
    int s = 0;
    for (int i = lo; i < hi; ++i) s += bh[i];
    part[t] = s;
    __syncthreads();
    for (int d = 1; d < 1024; d <<= 1) {
        int v = (t >= d) ? part[t - d] : 0;
        __syncthreads();
        part[t] += v;
        __syncthreads();
    }
    int run = t ? part[t - 1] : 0;
    for (int i = lo; i < hi; ++i) { int v = bh[i]; bs[i] = run; run += v; }
}

// ---------------- K3: bucketed scatter (blocks 0..255) ∥ transform0 (rest) -------
// rec is a single int: bits[26:18]=dst&511, bits[17:0]=kvidx (src*2+rel).

__global__ __launch_bounds__(256) void scatter_transform0_kernel(
    const int* __restrict__ src, const int* __restrict__ dst, const int* __restrict__ et,
    const int* __restrict__ bs, int* __restrict__ rec, int e,
    const float* __restrict__ x,
    const unsigned short* __restrict__ WtHi, const unsigned short* __restrict__ WtLo,
    const float* __restrict__ Qw, const float* __restrict__ Kw,
    unsigned short* __restrict__ yb, float* __restrict__ qv, float* __restrict__ kv, int n) {
    if (blockIdx.x < B_SCAT) {
        __shared__ int cur[NBUCK];
        int b = blockIdx.x;
        for (int j = threadIdx.x; j < NBUCK; j += 256) cur[j] = bs[j * B_SCAT + b];
        __syncthreads();
        int lo = b * CPB, hi = min(lo + CPB, e);
        for (int i = lo + threadIdx.x; i < hi; i += 256) {
            int d = dst[i];
            int pos = atomicAdd(&cur[d >> BSHIFT], 1);
            rec[pos] = ((d & ((1 << BSHIFT) - 1)) << 18) | (src[i] << 1) | et[i];
        }
    } else {
        transform_body<DIN, false>(x, nullptr, nullptr, nullptr, WtHi, WtLo,
                                   Qw, Kw, yb, qv, kv, (int)blockIdx.x - B_SCAT, n);
    }
}

// ---------------- K4: fine scatter + CSR off[] ----------------

__global__ __launch_bounds__(256) void fine_scatter_kernel(
    const int* __restrict__ rec, const int* __restrict__ bs,
    int* __restrict__ off, int* __restrict__ packed, int n, int e) {
    __shared__ int ldeg[1 << BSHIFT];
    __shared__ int lpos[1 << BSHIFT];
    int k = blockIdx.x, t = threadIdx.x;
    int nb0 = k << BSHIFT;
    ldeg[t] = 0;
    ldeg[t + 256] = 0;
    __syncthreads();
    int start = bs[k * B_SCAT];
    int end = (k + 1 < NBUCK) ? bs[(k + 1) * B_SCAT] : e;
    for (int i = start + t; i < end; i += 256)
        atomicAdd(&ldeg[rec[i] >> 18], 1);
    __syncthreads();
    lpos[t] = ldeg[t];
    lpos[t + 256] = ldeg[t + 256];
    __syncthreads();
    for (int d = 1; d < (1 << BSHIFT); d <<= 1) {
        int v0 = (t >= d) ? lpos[t - d] : 0;
        int v1 = (t + 256 >= d) ? lpos[t + 256 - d] : 0;
        __syncthreads();
        lpos[t] += v0;
        lpos[t + 256] += v1;
        __syncthreads();
    }
    int e0 = lpos[t] - ldeg[t];
    int e1 = lpos[t + 256] - ldeg[t + 256];
    __syncthreads();
    lpos[t] = start + e0;
    lpos[t + 256] = start + e1;
    int node0 = nb0 + t, node1 = nb0 + t + 256;
    if (node0 < n) off[node0] = start + e0;
    if (node1 < n) off[node1] = start + e1;
    if (k == 0 && t == 0) off[n] = e;
    __syncthreads();
    for (int i = start + t; i < end; i += 256) {
        int r = rec[i];
        int pos = atomicAdd(&lpos[r >> 18], 1);
        packed[pos] = r & 0x3FFFF;
    }
}

// ---------------- standalone hidden-layer transforms ----------------

template<int K>
__global__ __launch_bounds__(256) void transform_h_kernel(
    const float* __restrict__ xin, const float* __restrict__ stats,
    const float* __restrict__ gamma, const float* __restrict__ beta,
    const unsigned short* __restrict__ WtHi, const unsigned short* __restrict__ WtLo,
    const float* __restrict__ Qw, const float* __restrict__ Kw,
    unsigned short* __restrict__ yb, float* __restrict__ qv, float* __restrict__ kv, int n) {
    transform_body<K, true>(xin, stats, gamma, beta, WtHi, WtLo, Qw, Kw,
                            yb, qv, kv, blockIdx.x, n);
}

// ---------------- fused attention + aggregate + relu + BN stats ----------------

__global__ __launch_bounds__(256) void attn_kernel(
    const int* __restrict__ off, const int* __restrict__ packed,
    const unsigned short* __restrict__ y, const float* __restrict__ qv,
    const float* __restrict__ kv, const float* __restrict__ bias,
    float* __restrict__ hpre, float* __restrict__ stats, int n) {
    __shared__ float ssum[DH], ssq[DH];
    if (threadIdx.x < DH) { ssum[threadIdx.x] = 0.f; ssq[threadIdx.x] = 0.f; }
    __syncthreads();
    int lane = threadIdx.x & 31;
    int sub = threadIdx.x >> 5;
    int spb = blockDim.x >> 5;
    float rsum = 0.f, rsq = 0.f;
    float bl = bias[lane];
    for (int node = blockIdx.x * spb + sub; node < n; node += gridDim.x * spb) {
        int lo = off[node], hi = off[node + 1];
        float q0 = qv[node * 2], q1 = qv[node * 2 + 1];
        float acc0 = 0.f, acc1 = 0.f, acc2 = 0.f, acc3 = 0.f, wsum = 0.f;
        for (int base = lo; base < hi; base += 32) {
            int i = base + lane;
            float w = 0.f;
            int row = 0;
            if (i < hi) {
                int p = __builtin_nontemporal_load(packed + i);
                float ev = ((p & 1) ? q1 : q0) + kv[p];
                ev = ev > 0.f ? ev : NEG_SLOPE * ev;
                w = __expf(ev - 8.f);
                row = p << 5;
            }
            wsum += w;
            int cnt = min(32, hi - base);
            int j = 0;
            for (; j + 4 <= cnt; j += 4) {
                float w0 = __shfl(w, j, 32),     w1 = __shfl(w, j + 1, 32);
                float w2 = __shfl(w, j + 2, 32), w3 = __shfl(w, j + 3, 32);
                int r0 = __shfl(row, j, 32),     r1 = __shfl(row, j + 1, 32);
                int r2 = __shfl(row, j + 2, 32), r3 = __shfl(row, j + 3, 32);
                acc0 += w0 * h2f(y[r0 + lane]);
                acc1 += w1 * h2f(y[r1 + lane]);
                acc2 += w2 * h2f(y[r2 + lane]);
                acc3 += w3 * h2f(y[r3 + lane]);
            }
            for (; j < cnt; ++j) {
                float w0 = __shfl(w, j, 32);
                int r0 = __shfl(row, j, 32);
                acc0 += w0 * h2f(y[r0 + lane]);
            }
        }
        for (int d = 16; d; d >>= 1) wsum += __shfl_xor(wsum, d, 32);
        float h = fmaxf((acc0 + acc1 + acc2 + acc3) / (wsum + 1e-16f) + bl, 0.f);
        __builtin_nontemporal_store(h, &hpre[(size_t)node * DH + lane]);
        rsum += h;
        rsq += h * h;
    }
    atomicAdd(&ssum[lane], rsum);
    atomicAdd(&ssq[lane], rsq);
    __syncthreads();
    if (threadIdx.x < DH) {
        atomicAdd(&stats[threadIdx.x], ssum[threadIdx.x]);
        atomicAdd(&stats[DH + threadIdx.x], ssq[threadIdx.x]);
    }
}

// ---------------- final BN + MLP head ----------------

__global__ __launch_bounds__(256) void mlp_kernel(
    const float* __restrict__ hpre, const float* __restrict__ stats,
    const float* __restrict__ gamma, const float* __restrict__ beta,
    const float* __restrict__ mw1, const float* __restrict__ mb1,
    const float* __restrict__ mw2, const float* __restrict__ mb2,
    float* __restrict__ out, int n) {
    int g = (blockIdx.x * blockDim.x + threadIdx.x) >> 5;
    int lane = threadIdx.x & 31;
    if (g >= n) return;
    float mu = stats[lane] * (1.f / N_NODES);
    float var = stats[DH + lane] * (1.f / N_NODES) - mu * mu;
    float inv = rsqrtf(var + BN_EPS);
    float h = gamma[lane] * (hpre[(size_t)g * DH + lane] - mu) * inv + beta[lane];
    float a = mb1[lane];
#pragma unroll
    for (int f = 0; f < DH; ++f) a += __shfl(h, f, 32) * mw1[f * DH + lane];
    float s = 1.f / (1.f + __expf(-a));
    float o0 = s * mw2[lane * 2 + 0];
    float o1 = s * mw2[lane * 2 + 1];
    for (int d = 16; d; d >>= 1) {
        o0 += __shfl_xor(o0, d, 32);
        o1 += __shfl_xor(o1, d, 32);
    }
    if (lane == 0) {
        out[(size_t)g * 2 + 0] = o0 + mb2[0];
        out[(size_t)g * 2 + 1] = o1 + mb2[1];
    }
}

// ---------------- launch ----------------

extern "C" void kernel_launch(void* const* d_in, const int* in_sizes, int n_in,
                              void* d_out, int out_size, void* d_ws, size_t ws_size,
                              hipStream_t stream) {
    const float* x = (const float*)d_in[0];
    const int* edge_index = (const int*)d_in[1];
    const int* edge_type = (const int*)d_in[2];
    const float* w[3]  = {(const float*)d_in[3],  (const float*)d_in[9],  (const float*)d_in[15]};
    const float* aq[3] = {(const float*)d_in[4],  (const float*)d_in[10], (const float*)d_in[16]};
    const float* ak[3] = {(const float*)d_in[5],  (const float*)d_in[11], (const float*)d_in[17]};
    const float* bb[3] = {(const float*)d_in[6],  (const float*)d_in[12], (const float*)d_in[18]};
    const float* gm[3] = {(const float*)d_in[7],  (const float*)d_in[13], (const float*)d_in[19]};
    const float* be[3] = {(const float*)d_in[8],  (const float*)d_in[14], (const float*)d_in[20]};
    const float* mw1 = (const float*)d_in[21];
    const float* mb1 = (const float*)d_in[22];
    const float* mw2 = (const float*)d_in[23];
    const float* mb2 = (const float*)d_in[24];
    float* out = (float*)d_out;

    const int n = N_NODES, e = N_EDGES;
    char* ws = (char*)d_ws;
    auto alloc = [&](size_t bytes) {
        char* p = ws;
        ws += (bytes + 255) & ~(size_t)255;
        return p;
    };
    int* off      = (int*)alloc((size_t)(n + 1) * 4);
    int* bhist    = (int*)alloc((size_t)NBUCK * B_SCAT * 4);
    int* bscan    = (int*)alloc((size_t)NBUCK * B_SCAT * 4);
    int* rec      = (int*)alloc((size_t)e * 4);
    int* packed   = (int*)alloc((size_t)e * 4);
    unsigned short* yb = (unsigned short*)alloc((size_t)n * 2 * DH * 2);
    float* qv     = (float*)alloc((size_t)n * 2 * 4);
    float* kv     = (float*)alloc((size_t)n * 2 * 4);
    float* hpre   = (float*)alloc((size_t)n * DH * 4);
    float* stats  = (float*)alloc(3 * 2 * DH * 4);
    unsigned short* wt0h = (unsigned short*)alloc((size_t)64 * DIN * 2);
    unsigned short* wt0l = (unsigned short*)alloc((size_t)64 * DIN * 2);
    unsigned short* wt1h = (unsigned short*)alloc((size_t)64 * DH * 2);
    unsigned short* wt1l = (unsigned short*)alloc((size_t)64 * DH * 2);
    unsigned short* wt2h = (unsigned short*)alloc((size_t)64 * DH * 2);
    unsigned short* wt2l = (unsigned short*)alloc((size_t)64 * DH * 2);

    const int* src = edge_index;
    const int* dst = edge_index + e;

    int tblocks = (n + MT - 1) / MT;

    // K1: bucket hist + wconv + stats zero
    hist_wconv_kernel<<<B_SCAT + WCONV_BLOCKS, 256, 0, stream>>>(
        dst, bhist, e,
        w[0], wt0h, wt0l, w[1], wt1h, wt1l, w[2], wt2h, wt2l, stats);
    // K2: scan
    bucket_scan_kernel<<<1, 1024, 0, stream>>>(bhist, bscan, NBUCK * B_SCAT);
    // K3: bucketed scatter ∥ transform0
    scatter_transform0_kernel<<<B_SCAT + tblocks, 256, 0, stream>>>(
        src, dst, edge_type, bscan, rec, e,
        x, wt0h, wt0l, aq[0], ak[0], yb, qv, kv, n);
    // K4: fine scatter (+ CSR off)
    fine_scatter_kernel<<<NBUCK, 256, 0, stream>>>(rec, bscan, off, packed, n, e);

    // layer 0 attention
    attn_kernel<<<2048, 256, 0, stream>>>(off, packed, yb, qv, kv, bb[0], hpre, stats + 0 * 64, n);

    // layer 1
    transform_h_kernel<DH><<<tblocks, 256, 0, stream>>>(
        hpre, stats + 0 * 64, gm[0], be[0], wt1h, wt1l, aq[1], ak[1], yb, qv, kv, n);
    attn_kernel<<<2048, 256, 0, stream>>>(off, packed, yb, qv, kv, bb[1], hpre, stats + 1 * 64, n);

    // layer 2
    transform_h_kernel<DH><<<tblocks, 256, 0, stream>>>(
        hpre, stats + 1 * 64, gm[1], be[1], wt2h, wt2l, aq[2], ak[2], yb, qv, kv, n);
    attn_kernel<<<2048, 256, 0, stream>>>(off, packed, yb, qv, kv, bb[2], hpre, stats + 2 * 64, n);

    // final BN + MLP head
    mlp_kernel<<<((size_t)n * 32 + 255) / 256, 256, 0, stream>>>(
        hpre, stats + 2 * 64, gm[2], be[2], mw1, mb1, mw2, mb2, out, n);
}

// Round 10
// 447.210 us; speedup vs baseline: 1.0695x; 1.0207x over previous
//
#include <hip/hip_runtime.h>
#include <math.h>

#define N_NODES 100000
#define N_EDGES 1600000
#define DIN 128
#define DH 32
#define NEG_SLOPE 0.2f
#define BN_EPS 1e-5f
#define MT 64        // nodes per transform block
#define BSHIFT 9     // 512 nodes per bucket
#define NBUCK 196    // ceil(N_NODES / 512)
#define B_SCAT 256   // blocks for bucket hist/scatter
#define CPB ((N_EDGES + B_SCAT - 1) / B_SCAT)
#define WCONV_ELEMS (64 * DIN + 128 * DH)   // 12288
#define WCONV_BLOCKS ((WCONV_ELEMS + 255) / 256)
#define YSTRIDE 36      // ushorts per staged edge row (64B data + 8B pad, 8B-aligned)
#define SUBSTRIDE 1156  // ushorts per subwave region (2312B: 8B-aligned, 2-bank skew)

typedef __attribute__((ext_vector_type(8))) short short8;
typedef __attribute__((ext_vector_type(4))) float f32x4;

__device__ __forceinline__ unsigned short f2bf(float f) {
    unsigned int u = __float_as_uint(f);
    u = (u + 0x7FFFu + ((u >> 16) & 1u)) >> 16;
    return (unsigned short)u;
}
__device__ __forceinline__ float bf2f(unsigned short h) {
    return __uint_as_float((unsigned int)h << 16);
}
__device__ __forceinline__ unsigned short f2h(float f) {
    _Float16 hv = (_Float16)f;
    return __builtin_bit_cast(unsigned short, hv);
}
__device__ __forceinline__ float h2f(unsigned short h) {
    return (float)__builtin_bit_cast(_Float16, h);
}

// ---------------- shared transform body (MFMA, split-bf16) ----------------
// y[node][64] = X[node][K] @ Wmat[K][64]; y stored fp16; q/k row-dots fp32.

template<int K, bool FUSE_BN>
__device__ __forceinline__ void transform_body(
    const float* __restrict__ xin, const float* __restrict__ stats,
    const float* __restrict__ gamma, const float* __restrict__ beta,
    const unsigned short* __restrict__ WtHi, const unsigned short* __restrict__ WtLo,
    const float* __restrict__ Qw, const float* __restrict__ Kw,
    unsigned short* __restrict__ yb, float* __restrict__ qv, float* __restrict__ kv,
    int tile, int n) {
    constexpr int LDK = K + 8;
    constexpr int KT = K / 32;
    __shared__ unsigned short xs_hi[MT * LDK];
    __shared__ unsigned short xs_lo[MT * LDK];
    __shared__ float scs[DH], shs[DH];
    int tid = threadIdx.x;
    int base = tile * MT;

    if (FUSE_BN) {
        if (tid < DH) {
            float mu = stats[tid] * (1.f / N_NODES);
            float var = stats[DH + tid] * (1.f / N_NODES) - mu * mu;
            float inv = rsqrtf(var + BN_EPS);
            float sc = gamma[tid] * inv;
            scs[tid] = sc;
            shs[tid] = beta[tid] - mu * sc;
        }
        __syncthreads();
    }

    constexpr int CH = K / 4;
    for (int c = tid; c < MT * CH; c += 256) {
        int row = c / CH, c4 = c % CH;
        int node = base + row;
        float4 v = make_float4(0.f, 0.f, 0.f, 0.f);
        if (node < n) v = ((const float4*)(xin + (size_t)node * K))[c4];
        if (FUSE_BN) {
            int c0 = c4 * 4;
            v.x = v.x * scs[c0 + 0] + shs[c0 + 0];
            v.y = v.y * scs[c0 + 1] + shs[c0 + 1];
            v.z = v.z * scs[c0 + 2] + shs[c0 + 2];
            v.w = v.w * scs[c0 + 3] + shs[c0 + 3];
        }
        ushort4 hb = make_ushort4(f2bf(v.x), f2bf(v.y), f2bf(v.z), f2bf(v.w));
        ushort4 lb = make_ushort4(f2bf(v.x - bf2f(hb.x)), f2bf(v.y - bf2f(hb.y)),
                                  f2bf(v.z - bf2f(hb.z)), f2bf(v.w - bf2f(hb.w)));
        *(ushort4*)(&xs_hi[row * LDK + c4 * 4]) = hb;
        *(ushort4*)(&xs_lo[row * LDK + c4 * 4]) = lb;
    }
    __syncthreads();

    int lane = tid & 63;
    int wave = tid >> 6;
    int r16 = lane & 15, g = lane >> 4;
    int wrow = wave * 16;

    f32x4 acc[4];
#pragma unroll
    for (int nt = 0; nt < 4; ++nt) acc[nt] = f32x4{0.f, 0.f, 0.f, 0.f};

#pragma unroll
    for (int kt = 0; kt < KT; ++kt) {
        short8 a_hi = *(const short8*)(&xs_hi[(wrow + r16) * LDK + kt * 32 + g * 8]);
        short8 a_lo = *(const short8*)(&xs_lo[(wrow + r16) * LDK + kt * 32 + g * 8]);
#pragma unroll
        for (int nt = 0; nt < 4; ++nt) {
            const size_t bo = (size_t)(nt * 16 + r16) * K + kt * 32 + g * 8;
            short8 b_hi = *(const short8*)(WtHi + bo);
            short8 b_lo = *(const short8*)(WtLo + bo);
            acc[nt] = __builtin_amdgcn_mfma_f32_16x16x32_bf16(a_hi, b_hi, acc[nt], 0, 0, 0);
            acc[nt] = __builtin_amdgcn_mfma_f32_16x16x32_bf16(a_hi, b_lo, acc[nt], 0, 0, 0);
            acc[nt] = __builtin_amdgcn_mfma_f32_16x16x32_bf16(a_lo, b_hi, acc[nt], 0, 0, 0);
        }
    }

    float qp[2][4] = {{0.f, 0.f, 0.f, 0.f}, {0.f, 0.f, 0.f, 0.f}};
    float kp[2][4] = {{0.f, 0.f, 0.f, 0.f}, {0.f, 0.f, 0.f, 0.f}};
#pragma unroll
    for (int nt = 0; nt < 4; ++nt) {
        int col = nt * 16 + r16;
        int rr = col >> 5, cc = col & 31;
        float qw = Qw[rr * DH + cc], kw = Kw[rr * DH + cc];
#pragma unroll
        for (int j = 0; j < 4; ++j) {
            float v = acc[nt][j];
            qp[rr][j] += v * qw;
            kp[rr][j] += v * kw;
            int node = base + wrow + g * 4 + j;
            if (node < n) yb[(size_t)node * 64 + col] = f2h(v);
        }
    }
#pragma unroll
    for (int j = 0; j < 4; ++j) {
#pragma unroll
        for (int rr = 0; rr < 2; ++rr) {
            float q = qp[rr][j], k = kp[rr][j];
            for (int d = 8; d; d >>= 1) {
                q += __shfl_xor(q, d, 16);
                k += __shfl_xor(k, d, 16);
            }
            if (r16 == 0) {
                int node = base + wrow + g * 4 + j;
                if (node < n) {
                    qv[node * 2 + rr] = q;
                    kv[node * 2 + rr] = k;
                }
            }
        }
    }
}

// ---------------- K1: bucket hist + weight conversion + stats zero ----------------

__global__ __launch_bounds__(256) void hist_wconv_kernel(
    const int* __restrict__ dst, int* __restrict__ bh, int e,
    const float* __restrict__ w0, unsigned short* __restrict__ wt0h, unsigned short* __restrict__ wt0l,
    const float* __restrict__ w1, unsigned short* __restrict__ wt1h, unsigned short* __restrict__ wt1l,
    const float* __restrict__ w2, unsigned short* __restrict__ wt2h, unsigned short* __restrict__ wt2l,
    float* __restrict__ stats) {
    if (blockIdx.x < B_SCAT) {
        __shared__ int lh[NBUCK];
        for (int j = threadIdx.x; j < NBUCK; j += 256) lh[j] = 0;
        __syncthreads();
        int b = blockIdx.x;
        int lo = b * CPB, hi = min(lo + CPB, e);
        for (int i = lo + threadIdx.x; i < hi; i += 256)
            atomicAdd(&lh[dst[i] >> BSHIFT], 1);
        __syncthreads();
        for (int j = threadIdx.x; j < NBUCK; j += 256) bh[j * B_SCAT + b] = lh[j];
    } else {
        int i = (blockIdx.x - B_SCAT) * 256 + threadIdx.x;
        if (blockIdx.x == B_SCAT && threadIdx.x < 3 * 2 * DH) stats[threadIdx.x] = 0.f;
        const float* w;
        unsigned short *wh, *wl;
        int K, idx;
        if (i < 64 * DIN) { w = w0; wh = wt0h; wl = wt0l; K = DIN; idx = i; }
        else if (i < 64 * DIN + 64 * DH) { w = w1; wh = wt1h; wl = wt1l; K = DH; idx = i - 64 * DIN; }
        else if (i < 64 * DIN + 128 * DH) { w = w2; wh = wt2h; wl = wt2l; K = DH; idx = i - 64 * DIN - 64 * DH; }
        else return;
        int col = idx / K, k = idx % K;
        int r = col >> 5, c = col & 31;
        float v = w[(r * K + k) * DH + c];
        unsigned short h = f2bf(v);
        wh[idx] = h;
        wl[idx] = f2bf(v - bf2f(h));
    }
}

// ---------------- K2: exclusive scan over NBUCK*B_SCAT counters ----------------

__global__ __launch_bounds__(1024) void bucket_scan_kernel(
    const int* __restrict__ bh, int* __restrict__ bs, int total) {
    __shared__ int part[1024];
    int t = threadIdx.x;
    int chunk = (total + 1023) >> 10;
    int lo = t * chunk, hi = min(lo + chunk, total);
    int s = 0;
    for (int i = lo; i < hi; ++i) s += bh[i];
    part[t] = s;
    __syncthreads();
    for (int d = 1; d < 1024; d <<= 1) {
        int v = (t >= d) ? part[t - d] : 0;
        __syncthreads();
        part[t] += v;
        __syncthreads();
    }
    int run = t ? part[t - 1] : 0;
    for (int i = lo; i < hi; ++i) { int v = bh[i]; bs[i] = run; run += v; }
}

// ---------------- K3: bucketed scatter (blocks 0..255) ∥ transform0 (rest) -------
// rec is a single int: bits[26:18]=dst&511, bits[17:0]=kvidx (src*2+rel).

__global__ __launch_bounds__(256) void scatter_transform0_kernel(
    const int* __restrict__ src, const int* __restrict__ dst, const int* __restrict__ et,
    const int* __restrict__ bs, int* __restrict__ rec, int e,
    const float* __restrict__ x,
    const unsigned short* __restrict__ WtHi, const unsigned short* __restrict__ WtLo,
    const float* __restrict__ Qw, const float* __restrict__ Kw,
    unsigned short* __restrict__ yb, float* __restrict__ qv, float* __restrict__ kv, int n) {
    if (blockIdx.x < B_SCAT) {
        __shared__ int cur[NBUCK];
        int b = blockIdx.x;
        for (int j = threadIdx.x; j < NBUCK; j += 256) cur[j] = bs[j * B_SCAT + b];
        __syncthreads();
        int lo = b * CPB, hi = min(lo + CPB, e);
        for (int i = lo + threadIdx.x; i < hi; i += 256) {
            int d = dst[i];
            int pos = atomicAdd(&cur[d >> BSHIFT], 1);
            rec[pos] = ((d & ((1 << BSHIFT) - 1)) << 18) | (src[i] << 1) | et[i];
        }
    } else {
        transform_body<DIN, false>(x, nullptr, nullptr, nullptr, WtHi, WtLo,
                                   Qw, Kw, yb, qv, kv, (int)blockIdx.x - B_SCAT, n);
    }
}

// ---------------- K4: fine scatter + CSR off[] ----------------

__global__ __launch_bounds__(256) void fine_scatter_kernel(
    const int* __restrict__ rec, const int* __restrict__ bs,
    int* __restrict__ off, int* __restrict__ packed, int n, int e) {
    __shared__ int ldeg[1 << BSHIFT];
    __shared__ int lpos[1 << BSHIFT];
    int k = blockIdx.x, t = threadIdx.x;
    int nb0 = k << BSHIFT;
    ldeg[t] = 0;
    ldeg[t + 256] = 0;
    __syncthreads();
    int start = bs[k * B_SCAT];
    int end = (k + 1 < NBUCK) ? bs[(k + 1) * B_SCAT] : e;
    for (int i = start + t; i < end; i += 256)
        atomicAdd(&ldeg[rec[i] >> 18], 1);
    __syncthreads();
    lpos[t] = ldeg[t];
    lpos[t + 256] = ldeg[t + 256];
    __syncthreads();
    for (int d = 1; d < (1 << BSHIFT); d <<= 1) {
        int v0 = (t >= d) ? lpos[t - d] : 0;
        int v1 = (t + 256 >= d) ? lpos[t + 256 - d] : 0;
        __syncthreads();
        lpos[t] += v0;
        lpos[t + 256] += v1;
        __syncthreads();
    }
    int e0 = lpos[t] - ldeg[t];
    int e1 = lpos[t + 256] - ldeg[t + 256];
    __syncthreads();
    lpos[t] = start + e0;
    lpos[t + 256] = start + e1;
    int node0 = nb0 + t, node1 = nb0 + t + 256;
    if (node0 < n) off[node0] = start + e0;
    if (node1 < n) off[node1] = start + e1;
    if (k == 0 && t == 0) off[n] = e;
    __syncthreads();
    for (int i = start + t; i < end; i += 256) {
        int r = rec[i];
        int pos = atomicAdd(&lpos[r >> 18], 1);
        packed[pos] = r & 0x3FFFF;
    }
}

// ---------------- standalone hidden-layer transforms ----------------

template<int K>
__global__ __launch_bounds__(256) void transform_h_kernel(
    const float* __restrict__ xin, const float* __restrict__ stats,
    const float* __restrict__ gamma, const float* __restrict__ beta,
    const unsigned short* __restrict__ WtHi, const unsigned short* __restrict__ WtLo,
    const float* __restrict__ Qw, const float* __restrict__ Kw,
    unsigned short* __restrict__ yb, float* __restrict__ qv, float* __restrict__ kv, int n) {
    transform_body<K, true>(xin, stats, gamma, beta, WtHi, WtLo, Qw, Kw,
                            yb, qv, kv, blockIdx.x, n);
}

// ---------------- fused attention + aggregate + relu + BN stats ----------------
// Row-load + LDS-transpose gather: each lane owns one edge per 32-edge chunk,
// computes its weight locally (no shfl), and loads the edge's full 64B y-row
// (4 x dwordx4 -> 32 independent cache lines in flight per wave instruction).
// Rows+weights staged to LDS; lane=feature accumulation reads them back.
// Wave-local fence only (divergent trip counts forbid __syncthreads).

__global__ __launch_bounds__(256) void attn_kernel(
    const int* __restrict__ off, const int* __restrict__ packed,
    const unsigned short* __restrict__ y, const float* __restrict__ qv,
    const float* __restrict__ kv, const float* __restrict__ bias,
    float* __restrict__ hpre, float* __restrict__ stats, int n) {
    __shared__ float ssum[DH], ssq[DH];
    __shared__ unsigned short ylds[8 * SUBSTRIDE];
    __shared__ float wlds[8][32];
    if (threadIdx.x < DH) { ssum[threadIdx.x] = 0.f; ssq[threadIdx.x] = 0.f; }
    __syncthreads();
    int lane = threadIdx.x & 31;
    int sub = threadIdx.x >> 5;
    int spb = blockDim.x >> 5;
    unsigned short* ysub = ylds + sub * SUBSTRIDE;
    unsigned short* ywr = ysub + lane * YSTRIDE;
    float rsum = 0.f, rsq = 0.f;
    float bl = bias[lane];
    for (int node = blockIdx.x * spb + sub; node < n; node += gridDim.x * spb) {
        int lo = off[node], hi = off[node + 1];
        float q0 = qv[node * 2], q1 = qv[node * 2 + 1];
        float acc = 0.f, wsum = 0.f;
        for (int base = lo; base < hi; base += 32) {
            int i = base + lane;
            float w = 0.f;
            int row = 0;
            if (i < hi) {
                int p = __builtin_nontemporal_load(packed + i);
                float ev = ((p & 1) ? q1 : q0) + kv[p];
                ev = ev > 0.f ? ev : NEG_SLOPE * ev;
                w = __expf(ev - 8.f);
                row = p << 5;
            }
            wsum += w;
            // stage this lane's edge row (64B) + weight into LDS
            const uint4* yr = (const uint4*)(y + row);
            uint4 a = yr[0], b = yr[1], c = yr[2], d = yr[3];
            wlds[sub][lane] = w;
            ((uint2*)ywr)[0] = ((uint2*)&a)[0];
            ((uint2*)ywr)[1] = ((uint2*)&a)[1];
            ((uint2*)ywr)[2] = ((uint2*)&b)[0];
            ((uint2*)ywr)[3] = ((uint2*)&b)[1];
            ((uint2*)ywr)[4] = ((uint2*)&c)[0];
            ((uint2*)ywr)[5] = ((uint2*)&c)[1];
            ((uint2*)ywr)[6] = ((uint2*)&d)[0];
            ((uint2*)ywr)[7] = ((uint2*)&d)[1];
            asm volatile("s_waitcnt lgkmcnt(0)" ::: "memory");
            __builtin_amdgcn_sched_barrier(0);
            // lane = feature: accumulate over the 32 staged edges (w=0 pads tail)
            float a0 = 0.f, a1 = 0.f, a2 = 0.f, a3 = 0.f;
#pragma unroll
            for (int e2 = 0; e2 < 32; e2 += 4) {
                a0 += wlds[sub][e2 + 0] * h2f(ysub[(e2 + 0) * YSTRIDE + lane]);
                a1 += wlds[sub][e2 + 1] * h2f(ysub[(e2 + 1) * YSTRIDE + lane]);
                a2 += wlds[sub][e2 + 2] * h2f(ysub[(e2 + 2) * YSTRIDE + lane]);
                a3 += wlds[sub][e2 + 3] * h2f(ysub[(e2 + 3) * YSTRIDE + lane]);
            }
            acc += (a0 + a1) + (a2 + a3);
            asm volatile("s_waitcnt lgkmcnt(0)" ::: "memory");
            __builtin_amdgcn_sched_barrier(0);
        }
        for (int d = 16; d; d >>= 1) wsum += __shfl_xor(wsum, d, 32);
        float h = fmaxf(acc / (wsum + 1e-16f) + bl, 0.f);
        __builtin_nontemporal_store(h, &hpre[(size_t)node * DH + lane]);
        rsum += h;
        rsq += h * h;
    }
    atomicAdd(&ssum[lane], rsum);
    atomicAdd(&ssq[lane], rsq);
    __syncthreads();
    if (threadIdx.x < DH) {
        atomicAdd(&stats[threadIdx.x], ssum[threadIdx.x]);
        atomicAdd(&stats[DH + threadIdx.x], ssq[threadIdx.x]);
    }
}

// ---------------- final BN + MLP head ----------------

__global__ __launch_bounds__(256) void mlp_kernel(
    const float* __restrict__ hpre, const float* __restrict__ stats,
    const float* __restrict__ gamma, const float* __restrict__ beta,
    const float* __restrict__ mw1, const float* __restrict__ mb1,
    const float* __restrict__ mw2, const float* __restrict__ mb2,
    float* __restrict__ out, int n) {
    int g = (blockIdx.x * blockDim.x + threadIdx.x) >> 5;
    int lane = threadIdx.x & 31;
    if (g >= n) return;
    float mu = stats[lane] * (1.f / N_NODES);
    float var = stats[DH + lane] * (1.f / N_NODES) - mu * mu;
    float inv = rsqrtf(var + BN_EPS);
    float h = gamma[lane] * (hpre[(size_t)g * DH + lane] - mu) * inv + beta[lane];
    float a = mb1[lane];
#pragma unroll
    for (int f = 0; f < DH; ++f) a += __shfl(h, f, 32) * mw1[f * DH + lane];
    float s = 1.f / (1.f + __expf(-a));
    float o0 = s * mw2[lane * 2 + 0];
    float o1 = s * mw2[lane * 2 + 1];
    for (int d = 16; d; d >>= 1) {
        o0 += __shfl_xor(o0, d, 32);
        o1 += __shfl_xor(o1, d, 32);
    }
    if (lane == 0) {
        out[(size_t)g * 2 + 0] = o0 + mb2[0];
        out[(size_t)g * 2 + 1] = o1 + mb2[1];
    }
}

// ---------------- launch ----------------

extern "C" void kernel_launch(void* const* d_in, const int* in_sizes, int n_in,
                              void* d_out, int out_size, void* d_ws, size_t ws_size,
                              hipStream_t stream) {
    const float* x = (const float*)d_in[0];
    const int* edge_index = (const int*)d_in[1];
    const int* edge_type = (const int*)d_in[2];
    const float* w[3]  = {(const float*)d_in[3],  (const float*)d_in[9],  (const float*)d_in[15]};
    const float* aq[3] = {(const float*)d_in[4],  (const float*)d_in[10], (const float*)d_in[16]};
    const float* ak[3] = {(const float*)d_in[5],  (const float*)d_in[11], (const float*)d_in[17]};
    const float* bb[3] = {(const float*)d_in[6],  (const float*)d_in[12], (const float*)d_in[18]};
    const float* gm[3] = {(const float*)d_in[7],  (const float*)d_in[13], (const float*)d_in[19]};
    const float* be[3] = {(const float*)d_in[8],  (const float*)d_in[14], (const float*)d_in[20]};
    const float* mw1 = (const float*)d_in[21];
    const float* mb1 = (const float*)d_in[22];
    const float* mw2 = (const float*)d_in[23];
    const float* mb2 = (const float*)d_in[24];
    float* out = (float*)d_out;

    const int n = N_NODES, e = N_EDGES;
    char* ws = (char*)d_ws;
    auto alloc = [&](size_t bytes) {
        char* p = ws;
        ws += (bytes + 255) & ~(size_t)255;
        return p;
    };
    int* off      = (int*)alloc((size_t)(n + 1) * 4);
    int* bhist    = (int*)alloc((size_t)NBUCK * B_SCAT * 4);
    int* bscan    = (int*)alloc((size_t)NBUCK * B_SCAT * 4);
    int* rec      = (int*)alloc((size_t)e * 4);
    int* packed   = (int*)alloc((size_t)e * 4);
    unsigned short* yb = (unsigned short*)alloc((size_t)n * 2 * DH * 2);
    float* qv     = (float*)alloc((size_t)n * 2 * 4);
    float* kv     = (float*)alloc((size_t)n * 2 * 4);
    float* hpre   = (float*)alloc((size_t)n * DH * 4);
    float* stats  = (float*)alloc(3 * 2 * DH * 4);
    unsigned short* wt0h = (unsigned short*)alloc((size_t)64 * DIN * 2);
    unsigned short* wt0l = (unsigned short*)alloc((size_t)64 * DIN * 2);
    unsigned short* wt1h = (unsigned short*)alloc((size_t)64 * DH * 2);
    unsigned short* wt1l = (unsigned short*)alloc((size_t)64 * DH * 2);
    unsigned short* wt2h = (unsigned short*)alloc((size_t)64 * DH * 2);
    unsigned short* wt2l = (unsigned short*)alloc((size_t)64 * DH * 2);

    const int* src = edge_index;
    const int* dst = edge_index + e;

    int tblocks = (n + MT - 1) / MT;

    // K1: bucket hist + wconv + stats zero
    hist_wconv_kernel<<<B_SCAT + WCONV_BLOCKS, 256, 0, stream>>>(
        dst, bhist, e,
        w[0], wt0h, wt0l, w[1], wt1h, wt1l, w[2], wt2h, wt2l, stats);
    // K2: scan
    bucket_scan_kernel<<<1, 1024, 0, stream>>>(bhist, bscan, NBUCK * B_SCAT);
    // K3: bucketed scatter ∥ transform0
    scatter_transform0_kernel<<<B_SCAT + tblocks, 256, 0, stream>>>(
        src, dst, edge_type, bscan, rec, e,
        x, wt0h, wt0l, aq[0], ak[0], yb, qv, kv, n);
    // K4: fine scatter (+ CSR off)
    fine_scatter_kernel<<<NBUCK, 256, 0, stream>>>(rec, bscan, off, packed, n, e);

    // layer 0 attention
    attn_kernel<<<2048, 256, 0, stream>>>(off, packed, yb, qv, kv, bb[0], hpre, stats + 0 * 64, n);

    // layer 1
    transform_h_kernel<DH><<<tblocks, 256, 0, stream>>>(
        hpre, stats + 0 * 64, gm[0], be[0], wt1h, wt1l, aq[1], ak[1], yb, qv, kv, n);
    attn_kernel<<<2048, 256, 0, stream>>>(off, packed, yb, qv, kv, bb[1], hpre, stats + 1 * 64, n);

    // layer 2
    transform_h_kernel<DH><<<tblocks, 256, 0, stream>>>(
        hpre, stats + 1 * 64, gm[1], be[1], wt2h, wt2l, aq[2], ak[2], yb, qv, kv, n);
    attn_kernel<<<2048, 256, 0, stream>>>(off, packed, yb, qv, kv, bb[2], hpre, stats + 2 * 64, n);

    // final BN + MLP head
    mlp_kernel<<<((size_t)n * 32 + 255) / 256, 256, 0, stream>>>(
        hpre, stats + 2 * 64, gm[2], be[2], mw1, mb1, mw2, mb2, out, n);
}

// Round 11
// 383.090 us; speedup vs baseline: 1.2485x; 1.1674x over previous
//
#include <hip/hip_runtime.h>
#include <math.h>

#define N_NODES 100000
#define N_EDGES 1600000
#define DIN 128
#define DH 32
#define NEG_SLOPE 0.2f
#define BN_EPS 1e-5f
#define MT 64        // nodes per transform block
#define BSHIFT 9     // 512 nodes per bucket
#define NBUCK 196    // ceil(N_NODES / 512)
#define B_SCAT 256   // blocks for bucket hist/scatter
#define CPB ((N_EDGES + B_SCAT - 1) / B_SCAT)
#define WCONV_ELEMS (64 * DIN + 128 * DH)   // 12288
#define WCONV_BLOCKS ((WCONV_ELEMS + 255) / 256)
#define YSTRIDE 36      // ushorts per staged edge row (64B data + 8B pad, 8B-aligned)
#define SUBSTRIDE 1156  // ushorts per subwave region (2312B: 8B-aligned, 2-bank skew)
#define BTOT (NBUCK * B_SCAT)               // 50176 bucket counters
#define BNB ((BTOT + 511) / 512)            // 98 scan chunks

typedef __attribute__((ext_vector_type(8))) short short8;
typedef __attribute__((ext_vector_type(4))) float f32x4;

__device__ __forceinline__ unsigned short f2bf(float f) {
    unsigned int u = __float_as_uint(f);
    u = (u + 0x7FFFu + ((u >> 16) & 1u)) >> 16;
    return (unsigned short)u;
}
__device__ __forceinline__ float bf2f(unsigned short h) {
    return __uint_as_float((unsigned int)h << 16);
}
__device__ __forceinline__ unsigned short f2h(float f) {
    _Float16 hv = (_Float16)f;
    return __builtin_bit_cast(unsigned short, hv);
}
__device__ __forceinline__ float h2f(unsigned short h) {
    return (float)__builtin_bit_cast(_Float16, h);
}

// ---------------- shared transform body (MFMA, split-bf16) ----------------
// y[node][64] = X[node][K] @ Wmat[K][64]; y stored fp16; q/k row-dots fp32.

template<int K, bool FUSE_BN>
__device__ __forceinline__ void transform_body(
    const float* __restrict__ xin, const float* __restrict__ stats,
    const float* __restrict__ gamma, const float* __restrict__ beta,
    const unsigned short* __restrict__ WtHi, const unsigned short* __restrict__ WtLo,
    const float* __restrict__ Qw, const float* __restrict__ Kw,
    unsigned short* __restrict__ yb, float* __restrict__ qv, float* __restrict__ kv,
    int tile, int n) {
    constexpr int LDK = K + 8;
    constexpr int KT = K / 32;
    __shared__ unsigned short xs_hi[MT * LDK];
    __shared__ unsigned short xs_lo[MT * LDK];
    __shared__ float scs[DH], shs[DH];
    int tid = threadIdx.x;
    int base = tile * MT;

    if (FUSE_BN) {
        if (tid < DH) {
            float mu = stats[tid] * (1.f / N_NODES);
            float var = stats[DH + tid] * (1.f / N_NODES) - mu * mu;
            float inv = rsqrtf(var + BN_EPS);
            float sc = gamma[tid] * inv;
            scs[tid] = sc;
            shs[tid] = beta[tid] - mu * sc;
        }
        __syncthreads();
    }

    constexpr int CH = K / 4;
    for (int c = tid; c < MT * CH; c += 256) {
        int row = c / CH, c4 = c % CH;
        int node = base + row;
        float4 v = make_float4(0.f, 0.f, 0.f, 0.f);
        if (node < n) v = ((const float4*)(xin + (size_t)node * K))[c4];
        if (FUSE_BN) {
            int c0 = c4 * 4;
            v.x = v.x * scs[c0 + 0] + shs[c0 + 0];
            v.y = v.y * scs[c0 + 1] + shs[c0 + 1];
            v.z = v.z * scs[c0 + 2] + shs[c0 + 2];
            v.w = v.w * scs[c0 + 3] + shs[c0 + 3];
        }
        ushort4 hb = make_ushort4(f2bf(v.x), f2bf(v.y), f2bf(v.z), f2bf(v.w));
        ushort4 lb = make_ushort4(f2bf(v.x - bf2f(hb.x)), f2bf(v.y - bf2f(hb.y)),
                                  f2bf(v.z - bf2f(hb.z)), f2bf(v.w - bf2f(hb.w)));
        *(ushort4*)(&xs_hi[row * LDK + c4 * 4]) = hb;
        *(ushort4*)(&xs_lo[row * LDK + c4 * 4]) = lb;
    }
    __syncthreads();

    int lane = tid & 63;
    int wave = tid >> 6;
    int r16 = lane & 15, g = lane >> 4;
    int wrow = wave * 16;

    f32x4 acc[4];
#pragma unroll
    for (int nt = 0; nt < 4; ++nt) acc[nt] = f32x4{0.f, 0.f, 0.f, 0.f};

#pragma unroll
    for (int kt = 0; kt < KT; ++kt) {
        short8 a_hi = *(const short8*)(&xs_hi[(wrow + r16) * LDK + kt * 32 + g * 8]);
        short8 a_lo = *(const short8*)(&xs_lo[(wrow + r16) * LDK + kt * 32 + g * 8]);
#pragma unroll
        for (int nt = 0; nt < 4; ++nt) {
            const size_t bo = (size_t)(nt * 16 + r16) * K + kt * 32 + g * 8;
            short8 b_hi = *(const short8*)(WtHi + bo);
            short8 b_lo = *(const short8*)(WtLo + bo);
            acc[nt] = __builtin_amdgcn_mfma_f32_16x16x32_bf16(a_hi, b_hi, acc[nt], 0, 0, 0);
            acc[nt] = __builtin_amdgcn_mfma_f32_16x16x32_bf16(a_hi, b_lo, acc[nt], 0, 0, 0);
            acc[nt] = __builtin_amdgcn_mfma_f32_16x16x32_bf16(a_lo, b_hi, acc[nt], 0, 0, 0);
        }
    }

    float qp[2][4] = {{0.f, 0.f, 0.f, 0.f}, {0.f, 0.f, 0.f, 0.f}};
    float kp[2][4] = {{0.f, 0.f, 0.f, 0.f}, {0.f, 0.f, 0.f, 0.f}};
#pragma unroll
    for (int nt = 0; nt < 4; ++nt) {
        int col = nt * 16 + r16;
        int rr = col >> 5, cc = col & 31;
        float qw = Qw[rr * DH + cc], kw = Kw[rr * DH + cc];
#pragma unroll
        for (int j = 0; j < 4; ++j) {
            float v = acc[nt][j];
            qp[rr][j] += v * qw;
            kp[rr][j] += v * kw;
            int node = base + wrow + g * 4 + j;
            if (node < n) yb[(size_t)node * 64 + col] = f2h(v);
        }
    }
#pragma unroll
    for (int j = 0; j < 4; ++j) {
#pragma unroll
        for (int rr = 0; rr < 2; ++rr) {
            float q = qp[rr][j], k = kp[rr][j];
            for (int d = 8; d; d >>= 1) {
                q += __shfl_xor(q, d, 16);
                k += __shfl_xor(k, d, 16);
            }
            if (r16 == 0) {
                int node = base + wrow + g * 4 + j;
                if (node < n) {
                    qv[node * 2 + rr] = q;
                    kv[node * 2 + rr] = k;
                }
            }
        }
    }
}

// ---------------- K1: bucket hist + weight conversion + stats zero ----------------

__global__ __launch_bounds__(256) void hist_wconv_kernel(
    const int* __restrict__ dst, int* __restrict__ bh, int e,
    const float* __restrict__ w0, unsigned short* __restrict__ wt0h, unsigned short* __restrict__ wt0l,
    const float* __restrict__ w1, unsigned short* __restrict__ wt1h, unsigned short* __restrict__ wt1l,
    const float* __restrict__ w2, unsigned short* __restrict__ wt2h, unsigned short* __restrict__ wt2l,
    float* __restrict__ stats) {
    if (blockIdx.x < B_SCAT) {
        __shared__ int lh[NBUCK];
        for (int j = threadIdx.x; j < NBUCK; j += 256) lh[j] = 0;
        __syncthreads();
        int b = blockIdx.x;
        int lo = b * CPB, hi = min(lo + CPB, e);
        for (int i = lo + threadIdx.x; i < hi; i += 256)
            atomicAdd(&lh[dst[i] >> BSHIFT], 1);
        __syncthreads();
        for (int j = threadIdx.x; j < NBUCK; j += 256) bh[j * B_SCAT + b] = lh[j];
    } else {
        int i = (blockIdx.x - B_SCAT) * 256 + threadIdx.x;
        if (blockIdx.x == B_SCAT && threadIdx.x < 3 * 2 * DH) stats[threadIdx.x] = 0.f;
        const float* w;
        unsigned short *wh, *wl;
        int K, idx;
        if (i < 64 * DIN) { w = w0; wh = wt0h; wl = wt0l; K = DIN; idx = i; }
        else if (i < 64 * DIN + 64 * DH) { w = w1; wh = wt1h; wl = wt1l; K = DH; idx = i - 64 * DIN; }
        else if (i < 64 * DIN + 128 * DH) { w = w2; wh = wt2h; wl = wt2l; K = DH; idx = i - 64 * DIN - 64 * DH; }
        else return;
        int col = idx / K, k = idx % K;
        int r = col >> 5, c = col & 31;
        float v = w[(r * K + k) * DH + c];
        unsigned short h = f2bf(v);
        wh[idx] = h;
        wl[idx] = f2bf(v - bf2f(h));
    }
}

// ---------------- K2a/b/c: two-level exclusive scan over BTOT counters ----------------

__global__ __launch_bounds__(256) void bscan_part_kernel(
    const int* __restrict__ bh, int* __restrict__ part, int total) {
    __shared__ int sd[256];
    int b = blockIdx.x, t = threadIdx.x;
    int i0 = b * 512 + t;
    int s = 0;
    if (i0 < total) s += bh[i0];
    if (i0 + 256 < total) s += bh[i0 + 256];
    sd[t] = s;
    __syncthreads();
    for (int d = 128; d; d >>= 1) {
        if (t < d) sd[t] += sd[t + d];
        __syncthreads();
    }
    if (t == 0) part[b] = sd[0];
}

__global__ __launch_bounds__(128) void bscan_top_kernel(int* __restrict__ part, int nb) {
    __shared__ int sd[128];
    int t = threadIdx.x;
    sd[t] = (t < nb) ? part[t] : 0;
    __syncthreads();
    for (int d = 1; d < 128; d <<= 1) {
        int v = (t >= d) ? sd[t - d] : 0;
        __syncthreads();
        sd[t] += v;
        __syncthreads();
    }
    if (t < nb) part[t] = t ? sd[t - 1] : 0;
}

__global__ __launch_bounds__(512) void bscan_final_kernel(
    const int* __restrict__ bh, const int* __restrict__ part,
    int* __restrict__ bs, int total) {
    __shared__ int sd[512];
    int b = blockIdx.x, t = threadIdx.x;
    int i = b * 512 + t;
    int v0 = (i < total) ? bh[i] : 0;
    sd[t] = v0;
    __syncthreads();
    for (int d = 1; d < 512; d <<= 1) {
        int v = (t >= d) ? sd[t - d] : 0;
        __syncthreads();
        sd[t] += v;
        __syncthreads();
    }
    if (i < total) bs[i] = part[b] + sd[t] - v0;
}

// ---------------- K3: bucketed scatter (blocks 0..255) ∥ transform0 (rest) -------
// rec is a single int: bits[26:18]=dst&511, bits[17:0]=kvidx (src*2+rel).

__global__ __launch_bounds__(256) void scatter_transform0_kernel(
    const int* __restrict__ src, const int* __restrict__ dst, const int* __restrict__ et,
    const int* __restrict__ bs, int* __restrict__ rec, int e,
    const float* __restrict__ x,
    const unsigned short* __restrict__ WtHi, const unsigned short* __restrict__ WtLo,
    const float* __restrict__ Qw, const float* __restrict__ Kw,
    unsigned short* __restrict__ yb, float* __restrict__ qv, float* __restrict__ kv, int n) {
    if (blockIdx.x < B_SCAT) {
        __shared__ int cur[NBUCK];
        int b = blockIdx.x;
        for (int j = threadIdx.x; j < NBUCK; j += 256) cur[j] = bs[j * B_SCAT + b];
        __syncthreads();
        int lo = b * CPB, hi = min(lo + CPB, e);
        for (int i = lo + threadIdx.x; i < hi; i += 256) {
            int d = dst[i];
            int pos = atomicAdd(&cur[d >> BSHIFT], 1);
            rec[pos] = ((d & ((1 << BSHIFT) - 1)) << 18) | (src[i] << 1) | et[i];
        }
    } else {
        transform_body<DIN, false>(x, nullptr, nullptr, nullptr, WtHi, WtLo,
                                   Qw, Kw, yb, qv, kv, (int)blockIdx.x - B_SCAT, n);
    }
}

// ---------------- K4: fine scatter + CSR off[] ----------------

__global__ __launch_bounds__(256) void fine_scatter_kernel(
    const int* __restrict__ rec, const int* __restrict__ bs,
    int* __restrict__ off, int* __restrict__ packed, int n, int e) {
    __shared__ int ldeg[1 << BSHIFT];
    __shared__ int lpos[1 << BSHIFT];
    int k = blockIdx.x, t = threadIdx.x;
    int nb0 = k << BSHIFT;
    ldeg[t] = 0;
    ldeg[t + 256] = 0;
    __syncthreads();
    int start = bs[k * B_SCAT];
    int end = (k + 1 < NBUCK) ? bs[(k + 1) * B_SCAT] : e;
    for (int i = start + t; i < end; i += 256)
        atomicAdd(&ldeg[rec[i] >> 18], 1);
    __syncthreads();
    lpos[t] = ldeg[t];
    lpos[t + 256] = ldeg[t + 256];
    __syncthreads();
    for (int d = 1; d < (1 << BSHIFT); d <<= 1) {
        int v0 = (t >= d) ? lpos[t - d] : 0;
        int v1 = (t + 256 >= d) ? lpos[t + 256 - d] : 0;
        __syncthreads();
        lpos[t] += v0;
        lpos[t + 256] += v1;
        __syncthreads();
    }
    int e0 = lpos[t] - ldeg[t];
    int e1 = lpos[t + 256] - ldeg[t + 256];
    __syncthreads();
    lpos[t] = start + e0;
    lpos[t + 256] = start + e1;
    int node0 = nb0 + t, node1 = nb0 + t + 256;
    if (node0 < n) off[node0] = start + e0;
    if (node1 < n) off[node1] = start + e1;
    if (k == 0 && t == 0) off[n] = e;
    __syncthreads();
    for (int i = start + t; i < end; i += 256) {
        int r = rec[i];
        int pos = atomicAdd(&lpos[r >> 18], 1);
        packed[pos] = r & 0x3FFFF;
    }
}

// ---------------- standalone hidden-layer transforms ----------------

template<int K>
__global__ __launch_bounds__(256) void transform_h_kernel(
    const float* __restrict__ xin, const float* __restrict__ stats,
    const float* __restrict__ gamma, const float* __restrict__ beta,
    const unsigned short* __restrict__ WtHi, const unsigned short* __restrict__ WtLo,
    const float* __restrict__ Qw, const float* __restrict__ Kw,
    unsigned short* __restrict__ yb, float* __restrict__ qv, float* __restrict__ kv, int n) {
    transform_body<K, true>(xin, stats, gamma, beta, WtHi, WtLo, Qw, Kw,
                            yb, qv, kv, blockIdx.x, n);
}

// ---------------- fused attention + aggregate + relu + BN stats ----------------
// Row-load + LDS-transpose gather (round 10; at the random-line fetch floor).

__global__ __launch_bounds__(256) void attn_kernel(
    const int* __restrict__ off, const int* __restrict__ packed,
    const unsigned short* __restrict__ y, const float* __restrict__ qv,
    const float* __restrict__ kv, const float* __restrict__ bias,
    float* __restrict__ hpre, float* __restrict__ stats, int n) {
    __shared__ float ssum[DH], ssq[DH];
    __shared__ unsigned short ylds[8 * SUBSTRIDE];
    __shared__ float wlds[8][32];
    if (threadIdx.x < DH) { ssum[threadIdx.x] = 0.f; ssq[threadIdx.x] = 0.f; }
    __syncthreads();
    int lane = threadIdx.x & 31;
    int sub = threadIdx.x >> 5;
    int spb = blockDim.x >> 5;
    unsigned short* ysub = ylds + sub * SUBSTRIDE;
    unsigned short* ywr = ysub + lane * YSTRIDE;
    float rsum = 0.f, rsq = 0.f;
    float bl = bias[lane];
    for (int node = blockIdx.x * spb + sub; node < n; node += gridDim.x * spb) {
        int lo = off[node], hi = off[node + 1];
        float q0 = qv[node * 2], q1 = qv[node * 2 + 1];
        float acc = 0.f, wsum = 0.f;
        for (int base = lo; base < hi; base += 32) {
            int i = base + lane;
            float w = 0.f;
            int row = 0;
            if (i < hi) {
                int p = __builtin_nontemporal_load(packed + i);
                float ev = ((p & 1) ? q1 : q0) + kv[p];
                ev = ev > 0.f ? ev : NEG_SLOPE * ev;
                w = __expf(ev - 8.f);
                row = p << 5;
            }
            wsum += w;
            // stage this lane's edge row (64B) + weight into LDS
            const uint4* yr = (const uint4*)(y + row);
            uint4 a = yr[0], b = yr[1], c = yr[2], d = yr[3];
            wlds[sub][lane] = w;
            ((uint2*)ywr)[0] = ((uint2*)&a)[0];
            ((uint2*)ywr)[1] = ((uint2*)&a)[1];
            ((uint2*)ywr)[2] = ((uint2*)&b)[0];
            ((uint2*)ywr)[3] = ((uint2*)&b)[1];
            ((uint2*)ywr)[4] = ((uint2*)&c)[0];
            ((uint2*)ywr)[5] = ((uint2*)&c)[1];
            ((uint2*)ywr)[6] = ((uint2*)&d)[0];
            ((uint2*)ywr)[7] = ((uint2*)&d)[1];
            asm volatile("s_waitcnt lgkmcnt(0)" ::: "memory");
            __builtin_amdgcn_sched_barrier(0);
            // lane = feature: accumulate over the 32 staged edges (w=0 pads tail)
            float a0 = 0.f, a1 = 0.f, a2 = 0.f, a3 = 0.f;
#pragma unroll
            for (int e2 = 0; e2 < 32; e2 += 4) {
                a0 += wlds[sub][e2 + 0] * h2f(ysub[(e2 + 0) * YSTRIDE + lane]);
                a1 += wlds[sub][e2 + 1] * h2f(ysub[(e2 + 1) * YSTRIDE + lane]);
                a2 += wlds[sub][e2 + 2] * h2f(ysub[(e2 + 2) * YSTRIDE + lane]);
                a3 += wlds[sub][e2 + 3] * h2f(ysub[(e2 + 3) * YSTRIDE + lane]);
            }
            acc += (a0 + a1) + (a2 + a3);
            asm volatile("s_waitcnt lgkmcnt(0)" ::: "memory");
            __builtin_amdgcn_sched_barrier(0);
        }
        for (int d = 16; d; d >>= 1) wsum += __shfl_xor(wsum, d, 32);
        float h = fmaxf(acc / (wsum + 1e-16f) + bl, 0.f);
        __builtin_nontemporal_store(h, &hpre[(size_t)node * DH + lane]);
        rsum += h;
        rsq += h * h;
    }
    atomicAdd(&ssum[lane], rsum);
    atomicAdd(&ssq[lane], rsq);
    __syncthreads();
    if (threadIdx.x < DH) {
        atomicAdd(&stats[threadIdx.x], ssum[threadIdx.x]);
        atomicAdd(&stats[DH + threadIdx.x], ssq[threadIdx.x]);
    }
}

// ---------------- final BN + MLP head ----------------

__global__ __launch_bounds__(256) void mlp_kernel(
    const float* __restrict__ hpre, const float* __restrict__ stats,
    const float* __restrict__ gamma, const float* __restrict__ beta,
    const float* __restrict__ mw1, const float* __restrict__ mb1,
    const float* __restrict__ mw2, const float* __restrict__ mb2,
    float* __restrict__ out, int n) {
    int g = (blockIdx.x * blockDim.x + threadIdx.x) >> 5;
    int lane = threadIdx.x & 31;
    if (g >= n) return;
    float mu = stats[lane] * (1.f / N_NODES);
    float var = stats[DH + lane] * (1.f / N_NODES) - mu * mu;
    float inv = rsqrtf(var + BN_EPS);
    float h = gamma[lane] * (hpre[(size_t)g * DH + lane] - mu) * inv + beta[lane];
    float a = mb1[lane];
#pragma unroll
    for (int f = 0; f < DH; ++f) a += __shfl(h, f, 32) * mw1[f * DH + lane];
    float s = 1.f / (1.f + __expf(-a));
    float o0 = s * mw2[lane * 2 + 0];
    float o1 = s * mw2[lane * 2 + 1];
    for (int d = 16; d; d >>= 1) {
        o0 += __shfl_xor(o0, d, 32);
        o1 += __shfl_xor(o1, d, 32);
    }
    if (lane == 0) {
        out[(size_t)g * 2 + 0] = o0 + mb2[0];
        out[(size_t)g * 2 + 1] = o1 + mb2[1];
    }
}

// ---------------- launch ----------------

extern "C" void kernel_launch(void* const* d_in, const int* in_sizes, int n_in,
                              void* d_out, int out_size, void* d_ws, size_t ws_size,
                              hipStream_t stream) {
    const float* x = (const float*)d_in[0];
    const int* edge_index = (const int*)d_in[1];
    const int* edge_type = (const int*)d_in[2];
    const float* w[3]  = {(const float*)d_in[3],  (const float*)d_in[9],  (const float*)d_in[15]};
    const float* aq[3] = {(const float*)d_in[4],  (const float*)d_in[10], (const float*)d_in[16]};
    const float* ak[3] = {(const float*)d_in[5],  (const float*)d_in[11], (const float*)d_in[17]};
    const float* bb[3] = {(const float*)d_in[6],  (const float*)d_in[12], (const float*)d_in[18]};
    const float* gm[3] = {(const float*)d_in[7],  (const float*)d_in[13], (const float*)d_in[19]};
    const float* be[3] = {(const float*)d_in[8],  (const float*)d_in[14], (const float*)d_in[20]};
    const float* mw1 = (const float*)d_in[21];
    const float* mb1 = (const float*)d_in[22];
    const float* mw2 = (const float*)d_in[23];
    const float* mb2 = (const float*)d_in[24];
    float* out = (float*)d_out;

    const int n = N_NODES, e = N_EDGES;
    char* ws = (char*)d_ws;
    auto alloc = [&](size_t bytes) {
        char* p = ws;
        ws += (bytes + 255) & ~(size_t)255;
        return p;
    };
    int* off      = (int*)alloc((size_t)(n + 1) * 4);
    int* bhist    = (int*)alloc((size_t)BTOT * 4);
    int* bscan    = (int*)alloc((size_t)BTOT * 4);
    int* bpart    = (int*)alloc((size_t)BNB * 4);
    int* rec      = (int*)alloc((size_t)e * 4);
    int* packed   = (int*)alloc((size_t)e * 4);
    unsigned short* yb = (unsigned short*)alloc((size_t)n * 2 * DH * 2);
    float* qv     = (float*)alloc((size_t)n * 2 * 4);
    float* kv     = (float*)alloc((size_t)n * 2 * 4);
    float* hpre   = (float*)alloc((size_t)n * DH * 4);
    float* stats  = (float*)alloc(3 * 2 * DH * 4);
    unsigned short* wt0h = (unsigned short*)alloc((size_t)64 * DIN * 2);
    unsigned short* wt0l = (unsigned short*)alloc((size_t)64 * DIN * 2);
    unsigned short* wt1h = (unsigned short*)alloc((size_t)64 * DH * 2);
    unsigned short* wt1l = (unsigned short*)alloc((size_t)64 * DH * 2);
    unsigned short* wt2h = (unsigned short*)alloc((size_t)64 * DH * 2);
    unsigned short* wt2l = (unsigned short*)alloc((size_t)64 * DH * 2);

    const int* src = edge_index;
    const int* dst = edge_index + e;

    int tblocks = (n + MT - 1) / MT;

    // K1: bucket hist + wconv + stats zero
    hist_wconv_kernel<<<B_SCAT + WCONV_BLOCKS, 256, 0, stream>>>(
        dst, bhist, e,
        w[0], wt0h, wt0l, w[1], wt1h, wt1l, w[2], wt2h, wt2l, stats);
    // K2: two-level exclusive scan over bucket counters
    bscan_part_kernel<<<BNB, 256, 0, stream>>>(bhist, bpart, BTOT);
    bscan_top_kernel<<<1, 128, 0, stream>>>(bpart, BNB);
    bscan_final_kernel<<<BNB, 512, 0, stream>>>(bhist, bpart, bscan, BTOT);
    // K3: bucketed scatter ∥ transform0
    scatter_transform0_kernel<<<B_SCAT + tblocks, 256, 0, stream>>>(
        src, dst, edge_type, bscan, rec, e,
        x, wt0h, wt0l, aq[0], ak[0], yb, qv, kv, n);
    // K4: fine scatter (+ CSR off)
    fine_scatter_kernel<<<NBUCK, 256, 0, stream>>>(rec, bscan, off, packed, n, e);

    // layer 0 attention
    attn_kernel<<<2048, 256, 0, stream>>>(off, packed, yb, qv, kv, bb[0], hpre, stats + 0 * 64, n);

    // layer 1
    transform_h_kernel<DH><<<tblocks, 256, 0, stream>>>(
        hpre, stats + 0 * 64, gm[0], be[0], wt1h, wt1l, aq[1], ak[1], yb, qv, kv, n);
    attn_kernel<<<2048, 256, 0, stream>>>(off, packed, yb, qv, kv, bb[1], hpre, stats + 1 * 64, n);

    // layer 2
    transform_h_kernel<DH><<<tblocks, 256, 0, stream>>>(
        hpre, stats + 1 * 64, gm[1], be[1], wt2h, wt2l, aq[2], ak[2], yb, qv, kv, n);
    attn_kernel<<<2048, 256, 0, stream>>>(off, packed, yb, qv, kv, bb[2], hpre, stats + 2 * 64, n);

    // final BN + MLP head
    mlp_kernel<<<((size_t)n * 32 + 255) / 256, 256, 0, stream>>>(
        hpre, stats + 2 * 64, gm[2], be[2], mw1, mb1, mw2, mb2, out, n);
}

// Round 12
// 377.451 us; speedup vs baseline: 1.2672x; 1.0149x over previous
//
#include <hip/hip_runtime.h>
#include <math.h>

#define N_NODES 100000
#define N_EDGES 1600000
#define DIN 128
#define DH 32
#define NEG_SLOPE 0.2f
#define BN_EPS 1e-5f
#define MT 64        // nodes per transform block
#define BSHIFT 9     // 512 nodes per bucket
#define NBUCK 196    // ceil(N_NODES / 512)
#define NSB 256      // scatter blocks
#define SCPB ((N_EDGES + NSB - 1) / NSB)    // 6250 edges per scatter block
#define CAP 12288    // padded edges per bucket (max expected ~8.6K)
#define WCONV_ELEMS (64 * DIN + 128 * DH)   // 12288
#define WCONV_BLOCKS ((WCONV_ELEMS + 255) / 256)
#define YSTRIDE 36      // ushorts per staged edge row (64B data + 8B pad)
#define SUBSTRIDE 1156  // ushorts per subwave LDS region

typedef __attribute__((ext_vector_type(8))) short short8;
typedef __attribute__((ext_vector_type(4))) float f32x4;

__device__ __forceinline__ unsigned short f2bf(float f) {
    unsigned int u = __float_as_uint(f);
    u = (u + 0x7FFFu + ((u >> 16) & 1u)) >> 16;
    return (unsigned short)u;
}
__device__ __forceinline__ float bf2f(unsigned short h) {
    return __uint_as_float((unsigned int)h << 16);
}
__device__ __forceinline__ unsigned short f2h(float f) {
    _Float16 hv = (_Float16)f;
    return __builtin_bit_cast(unsigned short, hv);
}
__device__ __forceinline__ float h2f(unsigned short h) {
    return (float)__builtin_bit_cast(_Float16, h);
}

// ---------------- shared transform body (MFMA, split-bf16) ----------------

template<int K, bool FUSE_BN>
__device__ __forceinline__ void transform_body(
    const float* __restrict__ xin, const float* __restrict__ stats,
    const float* __restrict__ gamma, const float* __restrict__ beta,
    const unsigned short* __restrict__ WtHi, const unsigned short* __restrict__ WtLo,
    const float* __restrict__ Qw, const float* __restrict__ Kw,
    unsigned short* __restrict__ yb, float* __restrict__ qv, float* __restrict__ kv,
    int tile, int n) {
    constexpr int LDK = K + 8;
    constexpr int KT = K / 32;
    __shared__ unsigned short xs_hi[MT * LDK];
    __shared__ unsigned short xs_lo[MT * LDK];
    __shared__ float scs[DH], shs[DH];
    int tid = threadIdx.x;
    int base = tile * MT;

    if (FUSE_BN) {
        if (tid < DH) {
            float mu = stats[tid] * (1.f / N_NODES);
            float var = stats[DH + tid] * (1.f / N_NODES) - mu * mu;
            float inv = rsqrtf(var + BN_EPS);
            float sc = gamma[tid] * inv;
            scs[tid] = sc;
            shs[tid] = beta[tid] - mu * sc;
        }
        __syncthreads();
    }

    constexpr int CH = K / 4;
    for (int c = tid; c < MT * CH; c += 256) {
        int row = c / CH, c4 = c % CH;
        int node = base + row;
        float4 v = make_float4(0.f, 0.f, 0.f, 0.f);
        if (node < n) v = ((const float4*)(xin + (size_t)node * K))[c4];
        if (FUSE_BN) {
            int c0 = c4 * 4;
            v.x = v.x * scs[c0 + 0] + shs[c0 + 0];
            v.y = v.y * scs[c0 + 1] + shs[c0 + 1];
            v.z = v.z * scs[c0 + 2] + shs[c0 + 2];
            v.w = v.w * scs[c0 + 3] + shs[c0 + 3];
        }
        ushort4 hb = make_ushort4(f2bf(v.x), f2bf(v.y), f2bf(v.z), f2bf(v.w));
        ushort4 lb = make_ushort4(f2bf(v.x - bf2f(hb.x)), f2bf(v.y - bf2f(hb.y)),
                                  f2bf(v.z - bf2f(hb.z)), f2bf(v.w - bf2f(hb.w)));
        *(ushort4*)(&xs_hi[row * LDK + c4 * 4]) = hb;
        *(ushort4*)(&xs_lo[row * LDK + c4 * 4]) = lb;
    }
    __syncthreads();

    int lane = tid & 63;
    int wave = tid >> 6;
    int r16 = lane & 15, g = lane >> 4;
    int wrow = wave * 16;

    f32x4 acc[4];
#pragma unroll
    for (int nt = 0; nt < 4; ++nt) acc[nt] = f32x4{0.f, 0.f, 0.f, 0.f};

#pragma unroll
    for (int kt = 0; kt < KT; ++kt) {
        short8 a_hi = *(const short8*)(&xs_hi[(wrow + r16) * LDK + kt * 32 + g * 8]);
        short8 a_lo = *(const short8*)(&xs_lo[(wrow + r16) * LDK + kt * 32 + g * 8]);
#pragma unroll
        for (int nt = 0; nt < 4; ++nt) {
            const size_t bo = (size_t)(nt * 16 + r16) * K + kt * 32 + g * 8;
            short8 b_hi = *(const short8*)(WtHi + bo);
            short8 b_lo = *(const short8*)(WtLo + bo);
            acc[nt] = __builtin_amdgcn_mfma_f32_16x16x32_bf16(a_hi, b_hi, acc[nt], 0, 0, 0);
            acc[nt] = __builtin_amdgcn_mfma_f32_16x16x32_bf16(a_hi, b_lo, acc[nt], 0, 0, 0);
            acc[nt] = __builtin_amdgcn_mfma_f32_16x16x32_bf16(a_lo, b_hi, acc[nt], 0, 0, 0);
        }
    }

    float qp[2][4] = {{0.f, 0.f, 0.f, 0.f}, {0.f, 0.f, 0.f, 0.f}};
    float kp[2][4] = {{0.f, 0.f, 0.f, 0.f}, {0.f, 0.f, 0.f, 0.f}};
#pragma unroll
    for (int nt = 0; nt < 4; ++nt) {
        int col = nt * 16 + r16;
        int rr = col >> 5, cc = col & 31;
        float qw = Qw[rr * DH + cc], kw = Kw[rr * DH + cc];
#pragma unroll
        for (int j = 0; j < 4; ++j) {
            float v = acc[nt][j];
            qp[rr][j] += v * qw;
            kp[rr][j] += v * kw;
            int node = base + wrow + g * 4 + j;
            if (node < n) yb[(size_t)node * 64 + col] = f2h(v);
        }
    }
#pragma unroll
    for (int j = 0; j < 4; ++j) {
#pragma unroll
        for (int rr = 0; rr < 2; ++rr) {
            float q = qp[rr][j], k = kp[rr][j];
            for (int d = 8; d; d >>= 1) {
                q += __shfl_xor(q, d, 16);
                k += __shfl_xor(k, d, 16);
            }
            if (r16 == 0) {
                int node = base + wrow + g * 4 + j;
                if (node < n) {
                    qv[node * 2 + rr] = q;
                    kv[node * 2 + rr] = k;
                }
            }
        }
    }
}

// ---------------- K1: weight conversion + stats/cursor zero ----------------

__global__ __launch_bounds__(256) void init_wconv_kernel(
    const float* __restrict__ w0, unsigned short* __restrict__ wt0h, unsigned short* __restrict__ wt0l,
    const float* __restrict__ w1, unsigned short* __restrict__ wt1h, unsigned short* __restrict__ wt1l,
    const float* __restrict__ w2, unsigned short* __restrict__ wt2h, unsigned short* __restrict__ wt2l,
    float* __restrict__ stats, int* __restrict__ bcur) {
    int t = threadIdx.x;
    if (blockIdx.x == 0) {
        if (t < 3 * 2 * DH) stats[t] = 0.f;
        if (t < NBUCK) bcur[t] = 0;
    }
    int i = blockIdx.x * 256 + t;
    const float* w;
    unsigned short *wh, *wl;
    int K, idx;
    if (i < 64 * DIN) { w = w0; wh = wt0h; wl = wt0l; K = DIN; idx = i; }
    else if (i < 64 * DIN + 64 * DH) { w = w1; wh = wt1h; wl = wt1l; K = DH; idx = i - 64 * DIN; }
    else if (i < 64 * DIN + 128 * DH) { w = w2; wh = wt2h; wl = wt2l; K = DH; idx = i - 64 * DIN - 64 * DH; }
    else return;
    int col = idx / K, k = idx % K;
    int r = col >> 5, c = col & 31;
    float v = w[(r * K + k) * DH + c];
    unsigned short h = f2bf(v);
    wh[idx] = h;
    wl[idx] = f2bf(v - bf2f(h));
}

// ---------------- K2: atomic-reservation scatter (blocks 0..NSB-1) ∥ transform0 ---
// rec is a single int: bits[26:18]=dst&511, bits[17:0]=kvidx (src*2+rel).
// Bucket k's edges land in rec[k*CAP ... k*CAP + bcur[k]) via per-block range
// reservation (one global atomicAdd per (block,bucket)) — no global scan needed.

__global__ __launch_bounds__(256) void scatter_transform0_kernel(
    const int* __restrict__ src, const int* __restrict__ dst, const int* __restrict__ et,
    int* __restrict__ bcur, int* __restrict__ rec, int e,
    const float* __restrict__ x,
    const unsigned short* __restrict__ WtHi, const unsigned short* __restrict__ WtLo,
    const float* __restrict__ Qw, const float* __restrict__ Kw,
    unsigned short* __restrict__ yb, float* __restrict__ qv, float* __restrict__ kv, int n) {
    if (blockIdx.x < NSB) {
        __shared__ int lh[NBUCK];
        __shared__ int lbase[NBUCK];
        int b = blockIdx.x, t = threadIdx.x;
        for (int j = t; j < NBUCK; j += 256) lh[j] = 0;
        __syncthreads();
        int lo = b * SCPB, hi = min(lo + SCPB, e);
        for (int i = lo + t; i < hi; i += 256)
            atomicAdd(&lh[dst[i] >> BSHIFT], 1);
        __syncthreads();
        if (t < NBUCK) {
            int c = lh[t];
            lbase[t] = t * CAP + (c ? atomicAdd(&bcur[t], c) : 0);
            lh[t] = 0;
        }
        __syncthreads();
        for (int i = lo + t; i < hi; i += 256) {
            int d = dst[i];
            int k = d >> BSHIFT;
            int pos = lbase[k] + atomicAdd(&lh[k], 1);
            rec[pos] = ((d & ((1 << BSHIFT) - 1)) << 18) | (src[i] << 1) | et[i];
        }
    } else {
        transform_body<DIN, false>(x, nullptr, nullptr, nullptr, WtHi, WtLo,
                                   Qw, Kw, yb, qv, kv, (int)blockIdx.x - NSB, n);
    }
}

// ---------------- K3: fine scatter + per-node offS/offE ----------------

__global__ __launch_bounds__(256) void fine_scatter_kernel(
    const int* __restrict__ rec, const int* __restrict__ bcur,
    int* __restrict__ offS, int* __restrict__ offE, int* __restrict__ packed, int n) {
    __shared__ int ldeg[1 << BSHIFT];
    __shared__ int lpos[1 << BSHIFT];
    int k = blockIdx.x, t = threadIdx.x;
    int nb0 = k << BSHIFT;
    ldeg[t] = 0;
    ldeg[t + 256] = 0;
    __syncthreads();
    int start = k * CAP;
    int cnt = min(bcur[k], CAP);
    int end = start + cnt;
    for (int i = start + t; i < end; i += 256)
        atomicAdd(&ldeg[rec[i] >> 18], 1);
    __syncthreads();
    lpos[t] = ldeg[t];
    lpos[t + 256] = ldeg[t + 256];
    __syncthreads();
    for (int d = 1; d < (1 << BSHIFT); d <<= 1) {
        int v0 = (t >= d) ? lpos[t - d] : 0;
        int v1 = (t + 256 >= d) ? lpos[t + 256 - d] : 0;
        __syncthreads();
        lpos[t] += v0;
        lpos[t + 256] += v1;
        __syncthreads();
    }
    int e0 = lpos[t] - ldeg[t];          // exclusive
    int e1 = lpos[t + 256] - ldeg[t + 256];
    __syncthreads();
    lpos[t] = start + e0;
    lpos[t + 256] = start + e1;
    int node0 = nb0 + t, node1 = nb0 + t + 256;
    if (node0 < n) { offS[node0] = start + e0; offE[node0] = start + e0 + ldeg[t]; }
    if (node1 < n) { offS[node1] = start + e1; offE[node1] = start + e1 + ldeg[t + 256]; }
    __syncthreads();
    for (int i = start + t; i < end; i += 256) {
        int r = rec[i];
        int pos = atomicAdd(&lpos[r >> 18], 1);
        packed[pos] = r & 0x3FFFF;
    }
}

// ---------------- standalone hidden-layer transforms ----------------

template<int K>
__global__ __launch_bounds__(256) void transform_h_kernel(
    const float* __restrict__ xin, const float* __restrict__ stats,
    const float* __restrict__ gamma, const float* __restrict__ beta,
    const unsigned short* __restrict__ WtHi, const unsigned short* __restrict__ WtLo,
    const float* __restrict__ Qw, const float* __restrict__ Kw,
    unsigned short* __restrict__ yb, float* __restrict__ qv, float* __restrict__ kv, int n) {
    transform_body<K, true>(xin, stats, gamma, beta, WtHi, WtLo, Qw, Kw,
                            yb, qv, kv, blockIdx.x, n);
}

// ---------------- fused attention + aggregate + relu + BN stats ----------------
// Row-load + LDS-transpose gather (at the random-line fetch floor per r7/r10/r11).

__global__ __launch_bounds__(256) void attn_kernel(
    const int* __restrict__ offS, const int* __restrict__ offE,
    const int* __restrict__ packed,
    const unsigned short* __restrict__ y, const float* __restrict__ qv,
    const float* __restrict__ kv, const float* __restrict__ bias,
    float* __restrict__ hpre, float* __restrict__ stats, int n) {
    __shared__ float ssum[DH], ssq[DH];
    __shared__ unsigned short ylds[8 * SUBSTRIDE];
    __shared__ float wlds[8][32];
    if (threadIdx.x < DH) { ssum[threadIdx.x] = 0.f; ssq[threadIdx.x] = 0.f; }
    __syncthreads();
    int lane = threadIdx.x & 31;
    int sub = threadIdx.x >> 5;
    int spb = blockDim.x >> 5;
    unsigned short* ysub = ylds + sub * SUBSTRIDE;
    unsigned short* ywr = ysub + lane * YSTRIDE;
    float rsum = 0.f, rsq = 0.f;
    float bl = bias[lane];
    for (int node = blockIdx.x * spb + sub; node < n; node += gridDim.x * spb) {
        int lo = offS[node], hi = offE[node];
        float q0 = qv[node * 2], q1 = qv[node * 2 + 1];
        float acc = 0.f, wsum = 0.f;
        for (int base = lo; base < hi; base += 32) {
            int i = base + lane;
            float w = 0.f;
            int row = 0;
            if (i < hi) {
                int p = __builtin_nontemporal_load(packed + i);
                float ev = ((p & 1) ? q1 : q0) + kv[p];
                ev = ev > 0.f ? ev : NEG_SLOPE * ev;
                w = __expf(ev - 8.f);
                row = p << 5;
            }
            wsum += w;
            // stage this lane's edge row (64B) + weight into LDS
            const uint4* yr = (const uint4*)(y + row);
            uint4 a = yr[0], b = yr[1], c = yr[2], d = yr[3];
            wlds[sub][lane] = w;
            ((uint2*)ywr)[0] = ((uint2*)&a)[0];
            ((uint2*)ywr)[1] = ((uint2*)&a)[1];
            ((uint2*)ywr)[2] = ((uint2*)&b)[0];
            ((uint2*)ywr)[3] = ((uint2*)&b)[1];
            ((uint2*)ywr)[4] = ((uint2*)&c)[0];
            ((uint2*)ywr)[5] = ((uint2*)&c)[1];
            ((uint2*)ywr)[6] = ((uint2*)&d)[0];
            ((uint2*)ywr)[7] = ((uint2*)&d)[1];
            asm volatile("s_waitcnt lgkmcnt(0)" ::: "memory");
            __builtin_amdgcn_sched_barrier(0);
            // lane = feature: accumulate over the 32 staged edges (w=0 pads tail)
            float a0 = 0.f, a1 = 0.f, a2 = 0.f, a3 = 0.f;
#pragma unroll
            for (int e2 = 0; e2 < 32; e2 += 4) {
                a0 += wlds[sub][e2 + 0] * h2f(ysub[(e2 + 0) * YSTRIDE + lane]);
                a1 += wlds[sub][e2 + 1] * h2f(ysub[(e2 + 1) * YSTRIDE + lane]);
                a2 += wlds[sub][e2 + 2] * h2f(ysub[(e2 + 2) * YSTRIDE + lane]);
                a3 += wlds[sub][e2 + 3] * h2f(ysub[(e2 + 3) * YSTRIDE + lane]);
            }
            acc += (a0 + a1) + (a2 + a3);
            asm volatile("s_waitcnt lgkmcnt(0)" ::: "memory");
            __builtin_amdgcn_sched_barrier(0);
        }
        for (int d = 16; d; d >>= 1) wsum += __shfl_xor(wsum, d, 32);
        float h = fmaxf(acc / (wsum + 1e-16f) + bl, 0.f);
        __builtin_nontemporal_store(h, &hpre[(size_t)node * DH + lane]);
        rsum += h;
        rsq += h * h;
    }
    atomicAdd(&ssum[lane], rsum);
    atomicAdd(&ssq[lane], rsq);
    __syncthreads();
    if (threadIdx.x < DH) {
        atomicAdd(&stats[threadIdx.x], ssum[threadIdx.x]);
        atomicAdd(&stats[DH + threadIdx.x], ssq[threadIdx.x]);
    }
}

// ---------------- final BN + MLP head ----------------

__global__ __launch_bounds__(256) void mlp_kernel(
    const float* __restrict__ hpre, const float* __restrict__ stats,
    const float* __restrict__ gamma, const float* __restrict__ beta,
    const float* __restrict__ mw1, const float* __restrict__ mb1,
    const float* __restrict__ mw2, const float* __restrict__ mb2,
    float* __restrict__ out, int n) {
    int g = (blockIdx.x * blockDim.x + threadIdx.x) >> 5;
    int lane = threadIdx.x & 31;
    if (g >= n) return;
    float mu = stats[lane] * (1.f / N_NODES);
    float var = stats[DH + lane] * (1.f / N_NODES) - mu * mu;
    float inv = rsqrtf(var + BN_EPS);
    float h = gamma[lane] * (hpre[(size_t)g * DH + lane] - mu) * inv + beta[lane];
    float a = mb1[lane];
#pragma unroll
    for (int f = 0; f < DH; ++f) a += __shfl(h, f, 32) * mw1[f * DH + lane];
    float s = 1.f / (1.f + __expf(-a));
    float o0 = s * mw2[lane * 2 + 0];
    float o1 = s * mw2[lane * 2 + 1];
    for (int d = 16; d; d >>= 1) {
        o0 += __shfl_xor(o0, d, 32);
        o1 += __shfl_xor(o1, d, 32);
    }
    if (lane == 0) {
        out[(size_t)g * 2 + 0] = o0 + mb2[0];
        out[(size_t)g * 2 + 1] = o1 + mb2[1];
    }
}

// ---------------- launch ----------------

extern "C" void kernel_launch(void* const* d_in, const int* in_sizes, int n_in,
                              void* d_out, int out_size, void* d_ws, size_t ws_size,
                              hipStream_t stream) {
    const float* x = (const float*)d_in[0];
    const int* edge_index = (const int*)d_in[1];
    const int* edge_type = (const int*)d_in[2];
    const float* w[3]  = {(const float*)d_in[3],  (const float*)d_in[9],  (const float*)d_in[15]};
    const float* aq[3] = {(const float*)d_in[4],  (const float*)d_in[10], (const float*)d_in[16]};
    const float* ak[3] = {(const float*)d_in[5],  (const float*)d_in[11], (const float*)d_in[17]};
    const float* bb[3] = {(const float*)d_in[6],  (const float*)d_in[12], (const float*)d_in[18]};
    const float* gm[3] = {(const float*)d_in[7],  (const float*)d_in[13], (const float*)d_in[19]};
    const float* be[3] = {(const float*)d_in[8],  (const float*)d_in[14], (const float*)d_in[20]};
    const float* mw1 = (const float*)d_in[21];
    const float* mb1 = (const float*)d_in[22];
    const float* mw2 = (const float*)d_in[23];
    const float* mb2 = (const float*)d_in[24];
    float* out = (float*)d_out;

    const int n = N_NODES, e = N_EDGES;
    char* ws = (char*)d_ws;
    auto alloc = [&](size_t bytes) {
        char* p = ws;
        ws += (bytes + 255) & ~(size_t)255;
        return p;
    };
    int* offS     = (int*)alloc((size_t)n * 4);
    int* offE     = (int*)alloc((size_t)n * 4);
    int* bcur     = (int*)alloc((size_t)NBUCK * 4);
    int* rec      = (int*)alloc((size_t)(NBUCK + 1) * CAP * 4);
    int* packed   = (int*)alloc((size_t)(NBUCK + 1) * CAP * 4);
    unsigned short* yb = (unsigned short*)alloc((size_t)n * 2 * DH * 2);
    float* qv     = (float*)alloc((size_t)n * 2 * 4);
    float* kv     = (float*)alloc((size_t)n * 2 * 4);
    float* hpre   = (float*)alloc((size_t)n * DH * 4);
    float* stats  = (float*)alloc(3 * 2 * DH * 4);
    unsigned short* wt0h = (unsigned short*)alloc((size_t)64 * DIN * 2);
    unsigned short* wt0l = (unsigned short*)alloc((size_t)64 * DIN * 2);
    unsigned short* wt1h = (unsigned short*)alloc((size_t)64 * DH * 2);
    unsigned short* wt1l = (unsigned short*)alloc((size_t)64 * DH * 2);
    unsigned short* wt2h = (unsigned short*)alloc((size_t)64 * DH * 2);
    unsigned short* wt2l = (unsigned short*)alloc((size_t)64 * DH * 2);

    const int* src = edge_index;
    const int* dst = edge_index + e;

    int tblocks = (n + MT - 1) / MT;

    // K1: wconv + stats/cursor zero
    init_wconv_kernel<<<WCONV_BLOCKS, 256, 0, stream>>>(
        w[0], wt0h, wt0l, w[1], wt1h, wt1l, w[2], wt2h, wt2l, stats, bcur);
    // K2: atomic-reservation bucketed scatter ∥ transform0
    scatter_transform0_kernel<<<NSB + tblocks, 256, 0, stream>>>(
        src, dst, edge_type, bcur, rec, e,
        x, wt0h, wt0l, aq[0], ak[0], yb, qv, kv, n);
    // K3: fine scatter (+ per-node offS/offE)
    fine_scatter_kernel<<<NBUCK, 256, 0, stream>>>(rec, bcur, offS, offE, packed, n);

    // layer 0 attention
    attn_kernel<<<2048, 256, 0, stream>>>(offS, offE, packed, yb, qv, kv, bb[0], hpre, stats + 0 * 64, n);

    // layer 1
    transform_h_kernel<DH><<<tblocks, 256, 0, stream>>>(
        hpre, stats + 0 * 64, gm[0], be[0], wt1h, wt1l, aq[1], ak[1], yb, qv, kv, n);
    attn_kernel<<<2048, 256, 0, stream>>>(offS, offE, packed, yb, qv, kv, bb[1], hpre, stats + 1 * 64, n);

    // layer 2
    transform_h_kernel<DH><<<tblocks, 256, 0, stream>>>(
        hpre, stats + 1 * 64, gm[1], be[1], wt2h, wt2l, aq[2], ak[2], yb, qv, kv, n);
    attn_kernel<<<2048, 256, 0, stream>>>(offS, offE, packed, yb, qv, kv, bb[2], hpre, stats + 2 * 64, n);

    // final BN + MLP head
    mlp_kernel<<<((size_t)n * 32 + 255) / 256, 256, 0, stream>>>(
        hpre, stats + 2 * 64, gm[2], be[2], mw1, mb1, mw2, mb2, out, n);
}